// Round 6
// baseline (232.083 us; speedup 1.0000x reference)
//
#include <hip/hip_runtime.h>
#include <hip/hip_bf16.h>
#include <cstdint>

typedef uint16_t u16;
typedef __attribute__((ext_vector_type(8))) __bf16 bf16x8;
typedef __attribute__((ext_vector_type(4))) short s16x4;
typedef __attribute__((ext_vector_type(8))) short s16x8;
typedef __attribute__((ext_vector_type(4))) float f32x4;

#define MFMA(a, b, c) __builtin_amdgcn_mfma_f32_16x16x32_bf16((a), (b), (c), 0, 0, 0)
#define LOG100 4.6051701859880914f

__device__ __forceinline__ u16 f2bf(float f) {
  union { float f; uint32_t u; } v; v.f = f;
  uint32_t u = v.u;
  return (u16)((u + 0x7FFFu + ((u >> 16) & 1u)) >> 16);
}
__device__ __forceinline__ float bf2f(u16 s) {
  union { uint32_t u; float f; } v; v.u = ((uint32_t)s) << 16;
  return v.f;
}

union U8 { s16x8 s; bf16x8 b; };

__device__ __forceinline__ bf16x8 ld_bf8(const float* __restrict__ p) {
  float4 v0 = *(const float4*)p;
  float4 v1 = *(const float4*)(p + 4);
  U8 u;
  u.s[0] = (short)f2bf(v0.x); u.s[1] = (short)f2bf(v0.y);
  u.s[2] = (short)f2bf(v0.z); u.s[3] = (short)f2bf(v0.w);
  u.s[4] = (short)f2bf(v1.x); u.s[5] = (short)f2bf(v1.y);
  u.s[6] = (short)f2bf(v1.z); u.s[7] = (short)f2bf(v1.w);
  return u.b;
}
__device__ __forceinline__ bf16x8 zero_bf8() {
  U8 u;
  #pragma unroll
  for (int e = 0; e < 8; ++e) u.s[e] = 0;
  return u.b;
}

// ---------------- prep kernel: 17 blocks ----------------
// blocks 0..15 = (h, t):
//  t=0: BigB_M  rows l (Wk dim), cols e: M[l,e] = Wq[e].Wk[l]
//  t=1: BigB_Gq rows l, cols e: Wq[l].Wq[e]; virtual qb B-row -> augGq[e] = 2 Wq[e].qb
//  t=2: BigB_Gk rows l, cols e: Wk[l].Wk[e]; virtual qb B-row -> augM[e]  = Wk[e].qb
//  t=3: NT rows c, cols e: N[e,c] = sum_a Wv[e][ha] Wa[ha][c]; virtual vb A-row -> w4[c]
// block 16: bias table (bf16) + temp + cq4
__global__ __launch_bounds__(256) void k_prep(
    const float* __restrict__ Wq, const float* __restrict__ Wk,
    const float* __restrict__ Wv, const float* __restrict__ Wa,
    const float* __restrict__ Qb, const float* __restrict__ Vb,
    const float* __restrict__ rpos, const float* __restrict__ w1,
    const float* __restrict__ b1, const float* __restrict__ w2,
    const float* __restrict__ ls, const int* __restrict__ ridx,
    u16* __restrict__ BigB, u16* __restrict__ NT, u16* __restrict__ biasTb,
    float* __restrict__ augM, float* __restrict__ augGq,
    float* __restrict__ w4, float* __restrict__ cq4, float* __restrict__ temp) {
  __shared__ float tbl[225][4];
  __shared__ __align__(16) u16 sWaT[128 * 200];   // Wa^T chunk [c][a'], a' < 192
  const int bid = blockIdx.x;
  const int tid = threadIdx.x;

  if (bid == 16) {
    if (tid < 225) {
      float x0 = rpos[tid * 2 + 0], x1 = rpos[tid * 2 + 1];
      float a0 = 0.f, a1 = 0.f, a2 = 0.f, a3 = 0.f;
      for (int c = 0; c < 512; ++c) {
        float hv = fmaxf(fmaf(x0, w1[c], fmaf(x1, w1[512 + c], b1[c])), 0.f);
        a0 = fmaf(hv, w2[c * 4 + 0], a0);
        a1 = fmaf(hv, w2[c * 4 + 1], a1);
        a2 = fmaf(hv, w2[c * 4 + 2], a2);
        a3 = fmaf(hv, w2[c * 4 + 3], a3);
      }
      tbl[tid][0] = a0; tbl[tid][1] = a1; tbl[tid][2] = a2; tbl[tid][3] = a3;
    }
    if (tid < 4) temp[tid] = expf(fminf(ls[tid], LOG100));
    {
      int hh = tid >> 6, l = tid & 63;
      float s = 0.f;
      #pragma unroll
      for (int p = 0; p < 6; ++p) {
        float v = Qb[hh * 384 + l * 6 + p];
        s = fmaf(v, v, s);
      }
      s += __shfl_xor(s, 1); s += __shfl_xor(s, 2); s += __shfl_xor(s, 4);
      s += __shfl_xor(s, 8); s += __shfl_xor(s, 16); s += __shfl_xor(s, 32);
      if (l == 0) cq4[hh] = s;
    }
    __syncthreads();
    for (int it = 0; it < 64; ++it) {
      int gid = it * 256 + tid;
      int h = gid >> 12;
      int rem = gid & 4095;
      int q = rem >> 6, p = rem & 63;
      int ii = ((p >> 3) << 3) + (q >> 3);
      int jj = ((p & 7) << 3) + (q & 7);
      float v = tbl[ridx[ii * 64 + jj]][h];
      biasTb[gid] = f2bf(16.f / (1.f + expf(-v)));
    }
    return;
  }

  const int h = bid >> 2, t = bid & 3;
  const int wid = tid >> 6, lane = tid & 63;
  const int l15 = lane & 15, lk4 = (lane >> 4) << 2, lk8 = (lane >> 4) << 3;
  const f32x4 zf4 = {0.f, 0.f, 0.f, 0.f};

  f32x4 acc[2][8];
  #pragma unroll
  for (int mm = 0; mm < 2; ++mm)
    #pragma unroll
    for (int nn = 0; nn < 8; ++nn) acc[mm][nn] = zf4;

  if (t < 3) {
    const float* A = (t == 2) ? Wk : Wq;
    const float* B = (t == 0) ? Wk : ((t == 1) ? Wq : Wk);
    f32x4 accq[2] = {zf4, zf4};
    for (int ks = 0; ks < 12; ++ks) {
      const int koff = h * 384 + ks * 32 + lk8;
      bf16x8 a[2], bw[8];
      #pragma unroll
      for (int mm = 0; mm < 2; ++mm)
        a[mm] = ld_bf8(&A[(size_t)(wid * 32 + mm * 16 + l15) * 1536 + koff]);
      #pragma unroll
      for (int nn = 0; nn < 8; ++nn)
        bw[nn] = ld_bf8(&B[(size_t)(nn * 16 + l15) * 1536 + koff]);
      #pragma unroll
      for (int nn = 0; nn < 8; ++nn)
        #pragma unroll
        for (int mm = 0; mm < 2; ++mm)
          acc[mm][nn] = MFMA(a[mm], bw[nn], acc[mm][nn]);
      if (t >= 1) {
        bf16x8 bq = (l15 == 0) ? ld_bf8(&Qb[koff]) : zero_bf8();
        #pragma unroll
        for (int mm = 0; mm < 2; ++mm) accq[mm] = MFMA(a[mm], bq, accq[mm]);
      }
    }
    u16* dst = BigB + (size_t)((h * 3 + t) * 128) * 128;
    #pragma unroll
    for (int mm = 0; mm < 2; ++mm) {
      const int k0 = wid * 32 + mm * 16 + lk4;
      #pragma unroll
      for (int nn = 0; nn < 8; ++nn) {
        s16x4 u;
        u[0] = (short)f2bf(acc[mm][nn][0]); u[1] = (short)f2bf(acc[mm][nn][1]);
        u[2] = (short)f2bf(acc[mm][nn][2]); u[3] = (short)f2bf(acc[mm][nn][3]);
        *(s16x4*)&dst[(nn * 16 + l15) * 128 + k0] = u;
      }
    }
    if (t >= 1 && l15 == 0) {
      float* tgt = (t == 1) ? augGq : augM;
      const float sc = (t == 1) ? 2.f : 1.f;
      #pragma unroll
      for (int mm = 0; mm < 2; ++mm)
        #pragma unroll
        for (int r = 0; r < 4; ++r)
          tgt[h * 128 + wid * 32 + mm * 16 + lk4 + r] = sc * accq[mm][r];
    }
  } else {
    f32x4 accv[8];
    #pragma unroll
    for (int nn = 0; nn < 8; ++nn) accv[nn] = zf4;
    for (int chunk = 0; chunk < 2; ++chunk) {
      __syncthreads();
      // stage Wa_h^T chunk: a' in [0,192), coalesced float4 reads
      for (int it = 0; it < 24; ++it) {
        int idx = it * 256 + tid;                // 6144 float4
        int a = idx >> 5;                        // 0..191
        int c4 = (idx & 31) << 2;                // 0..124
        const float4 v = *(const float4*)&Wa[(size_t)(h * 384 + chunk * 192 + a) * 128 + c4];
        sWaT[(c4 + 0) * 200 + a] = f2bf(v.x);
        sWaT[(c4 + 1) * 200 + a] = f2bf(v.y);
        sWaT[(c4 + 2) * 200 + a] = f2bf(v.z);
        sWaT[(c4 + 3) * 200 + a] = f2bf(v.w);
      }
      __syncthreads();
      for (int ks2 = 0; ks2 < 6; ++ks2) {
        const int koff = h * 384 + chunk * 192 + ks2 * 32 + lk8;
        const int lkoff = ks2 * 32 + lk8;
        bf16x8 a[2], bw[8];
        #pragma unroll
        for (int mm = 0; mm < 2; ++mm)
          a[mm] = ld_bf8(&Wv[(size_t)(wid * 32 + mm * 16 + l15) * 1536 + koff]);
        #pragma unroll
        for (int nn = 0; nn < 8; ++nn)
          bw[nn] = *(const bf16x8*)&sWaT[(nn * 16 + l15) * 200 + lkoff];
        #pragma unroll
        for (int nn = 0; nn < 8; ++nn)
          #pragma unroll
          for (int mm = 0; mm < 2; ++mm)
            acc[mm][nn] = MFMA(a[mm], bw[nn], acc[mm][nn]);
        if (wid == 0) {
          bf16x8 av = (l15 == 0) ? ld_bf8(&Vb[koff]) : zero_bf8();
          #pragma unroll
          for (int nn = 0; nn < 8; ++nn) accv[nn] = MFMA(av, bw[nn], accv[nn]);
        }
      }
    }
    u16* dst = NT + (size_t)(h * 128) * 128;
    #pragma unroll
    for (int mm = 0; mm < 2; ++mm) {
      const int k0 = wid * 32 + mm * 16 + lk4;
      #pragma unroll
      for (int nn = 0; nn < 8; ++nn) {
        s16x4 u;
        u[0] = (short)f2bf(acc[mm][nn][0]); u[1] = (short)f2bf(acc[mm][nn][1]);
        u[2] = (short)f2bf(acc[mm][nn][2]); u[3] = (short)f2bf(acc[mm][nn][3]);
        *(s16x4*)&dst[(nn * 16 + l15) * 128 + k0] = u;
      }
    }
    if (wid == 0 && lane < 16) {
      #pragma unroll
      for (int nn = 0; nn < 8; ++nn)
        w4[h * 128 + nn * 16 + lane] = accv[nn][0];
    }
  }
}

// ---------------- main fused kernel ----------------
// 1 block = 2 windows. 1024 threads = 16 waves (wave>>3 = window). 129 KB dyn LDS.
// Per window (8 waves), per head:
//  X = {out += P_{h-1} EN_{h-1}; Z = G E^T (diag partials); T1 = E M^T + augM}
//  Y = {S = T1 E^T -> P; EN = E N + w4 (transposed store)}
__global__ __launch_bounds__(1024, 1) void k_msa(
    const float* __restrict__ E,
    const u16* __restrict__ BigB, const u16* __restrict__ NT,
    const u16* __restrict__ biasTb,
    const float* __restrict__ augM, const float* __restrict__ augGq,
    const float* __restrict__ w4, const float* __restrict__ cq4,
    const float* __restrict__ temp, const float* __restrict__ Ab,
    float* __restrict__ out) {
  extern __shared__ __align__(16) char lds[];
  u16* sEb    = (u16*)(lds);               // 2 x [64][136]
  u16* sT1b   = (u16*)(lds + 34816);       // 2 x [64][136]
  u16* sPb    = (u16*)(lds + 69632);       // 2 x [64][72]
  u16* sENTb  = (u16*)(lds + 88064);       // 2 x [128][72]
  float* sDqb = (float*)(lds + 124928);    // 2 x [4][64]
  float* sDkb = (float*)(lds + 126976);    // 2 x [4][64]

  const int tid = threadIdx.x;
  const int wid = tid >> 6;
  const int w   = wid >> 3;       // window index in block
  const int wv  = wid & 7;        // wave-in-window
  const int lane = tid & 63;
  const int l15 = lane & 15;
  const int lk4 = (lane >> 4) << 2;
  const int lk8 = (lane >> 4) << 3;
  const int mt = wv >> 1;         // PV/S row tile
  const int ch = wv & 1;          // PV col half
  const int j0 = ch * 32;         // S col base
  const int onc = wv << 4;        // T1/EN col strip

  u16* sE   = sEb + w * 8704;
  u16* sT1  = sT1b + w * 8704;
  u16* sP   = sPb + w * 4608;
  u16* sENT = sENTb + w * 9216;
  float* sDqp = sDqb + w * 256;
  float* sDkp = sDkb + w * 256;

  // ---- stage E for both windows (f32 -> bf16)
  {
    const float4* E4 = (const float4*)(E + (size_t)blockIdx.x * 16384);
    #pragma unroll
    for (int it = 0; it < 4; ++it) {
      int i = tid + it * 1024;                  // 4096 float4
      float4 v = E4[i];
      int ww = i >> 11;
      int idx = i & 2047;
      int row = idx >> 5, c = (idx & 31) << 2;
      s16x4 u;
      u[0] = (short)f2bf(v.x); u[1] = (short)f2bf(v.y);
      u[2] = (short)f2bf(v.z); u[3] = (short)f2bf(v.w);
      *(s16x4*)&sEb[ww * 8704 + row * 136 + c] = u;
    }
  }
  __syncthreads();

  const f32x4 zf4 = {0.f, 0.f, 0.f, 0.f};
  f32x4 oacc[4];
  #pragma unroll
  for (int n = 0; n < 4; ++n) oacc[n] = zf4;

  for (int h = 0; h < 4; ++h) {
    // ================= X phase =================
    if (h > 0) {
      #pragma unroll
      for (int ks = 0; ks < 2; ++ks) {
        const int koff = ks * 32 + lk8;
        bf16x8 a = *(const bf16x8*)&sP[(mt * 16 + l15) * 72 + koff];
        #pragma unroll
        for (int n = 0; n < 4; ++n) {
          bf16x8 bw = *(const bf16x8*)&sENT[(ch * 64 + n * 16 + l15) * 72 + koff];
          oacc[n] = MFMA(a, bw, oacc[n]);
        }
      }
    }
    // Z = G E^T; wave owns 32 G rows x all 64 cols
    {
      const int zt = (wv < 4) ? 1 : 2;
      const int rw = (wv & 3) * 32;
      const u16* G = BigB + (size_t)((h * 3 + zt) * 128 + rw) * 128;
      f32x4 z[2][4];
      #pragma unroll
      for (int mm = 0; mm < 2; ++mm)
        #pragma unroll
        for (int n = 0; n < 4; ++n) z[mm][n] = zf4;
      #pragma unroll
      for (int ks = 0; ks < 4; ++ks) {
        const int koff = ks * 32 + lk8;
        bf16x8 a0 = *(const bf16x8*)&G[(l15) * 128 + koff];
        bf16x8 a1 = *(const bf16x8*)&G[(16 + l15) * 128 + koff];
        #pragma unroll
        for (int n = 0; n < 4; ++n) {
          bf16x8 bw = *(const bf16x8*)&sE[(n * 16 + l15) * 136 + koff];
          z[0][n] = MFMA(a0, bw, z[0][n]);
          z[1][n] = MFMA(a1, bw, z[1][n]);
        }
      }
      float aq[2][4];
      #pragma unroll
      for (int mm = 0; mm < 2; ++mm)
        #pragma unroll
        for (int r = 0; r < 4; ++r)
          aq[mm][r] = (wv < 4) ? augGq[h * 128 + rw + mm * 16 + lk4 + r] : 0.f;
      #pragma unroll
      for (int n = 0; n < 4; ++n) {
        const int j = n * 16 + l15;
        float p = 0.f;
        #pragma unroll
        for (int mm = 0; mm < 2; ++mm)
          #pragma unroll
          for (int r = 0; r < 4; ++r)
            p = fmaf(z[mm][n][r] + aq[mm][r],
                     bf2f(sE[j * 136 + rw + mm * 16 + lk4 + r]), p);
        p += __shfl_xor(p, 16);
        p += __shfl_xor(p, 32);
        if (lane < 16) {
          if (wv < 4) sDqp[(wv & 3) * 64 + j] = p;
          else        sDkp[(wv & 3) * 64 + j] = p;
        }
      }
    }
    // T1 = E M^T + augM ; col strip per wave
    {
      const u16* M = BigB + (size_t)(h * 3 * 128) * 128;
      f32x4 t1[4];
      #pragma unroll
      for (int m = 0; m < 4; ++m) t1[m] = zf4;
      #pragma unroll
      for (int ks = 0; ks < 4; ++ks) {
        const int koff = ks * 32 + lk8;
        bf16x8 bw = *(const bf16x8*)&M[(onc + l15) * 128 + koff];
        #pragma unroll
        for (int m = 0; m < 4; ++m) {
          bf16x8 a = *(const bf16x8*)&sE[(m * 16 + l15) * 136 + koff];
          t1[m] = MFMA(a, bw, t1[m]);
        }
      }
      const float ta = augM[h * 128 + onc + l15];
      const int col = onc + l15;
      #pragma unroll
      for (int m = 0; m < 4; ++m)
        #pragma unroll
        for (int r = 0; r < 4; ++r)
          sT1[(m * 16 + lk4 + r) * 136 + col] = f2bf(t1[m][r] + ta);
    }
    __syncthreads();
    // ================= Y phase =================
    {
      // S = T1 E^T (K=128)
      f32x4 s2[2] = {zf4, zf4};
      #pragma unroll
      for (int ks = 0; ks < 4; ++ks) {
        const int koff = ks * 32 + lk8;
        bf16x8 a = *(const bf16x8*)&sT1[(mt * 16 + l15) * 136 + koff];
        #pragma unroll
        for (int n = 0; n < 2; ++n) {
          bf16x8 bw = *(const bf16x8*)&sE[(j0 + n * 16 + l15) * 136 + koff];
          s2[n] = MFMA(a, bw, s2[n]);
        }
      }
      // EN = E N + w4 (K=128)
      const u16* Nt = NT + (size_t)(h * 128) * 128;
      f32x4 en[4];
      #pragma unroll
      for (int m = 0; m < 4; ++m) en[m] = zf4;
      #pragma unroll
      for (int ks = 0; ks < 4; ++ks) {
        const int koff = ks * 32 + lk8;
        bf16x8 bw = *(const bf16x8*)&Nt[(onc + l15) * 128 + koff];
        #pragma unroll
        for (int m = 0; m < 4; ++m) {
          bf16x8 a = *(const bf16x8*)&sE[(m * 16 + l15) * 136 + koff];
          en[m] = MFMA(a, bw, en[m]);
        }
      }
      // P epilogue
      const float th = temp[h], cqh = cq4[h];
      const int i0 = mt * 16 + lk4;
      f32x4 dq = *(const f32x4*)&sDqp[0 * 64 + i0];
      dq += *(const f32x4*)&sDqp[1 * 64 + i0];
      dq += *(const f32x4*)&sDqp[2 * 64 + i0];
      dq += *(const f32x4*)&sDqp[3 * 64 + i0];
      float qs[4];
      #pragma unroll
      for (int r = 0; r < 4; ++r)
        qs[r] = th / fmaxf(sqrtf(fmaxf(dq[r] + cqh, 0.f)), 1e-12f);
      #pragma unroll
      for (int n = 0; n < 2; ++n) {
        const int j = j0 + n * 16 + l15;
        const float dk = sDkp[0 * 64 + j] + sDkp[1 * 64 + j] +
                         sDkp[2 * 64 + j] + sDkp[3 * 64 + j];
        const float ki = 1.f / fmaxf(sqrtf(fmaxf(dk, 0.f)), 1e-12f);
        s16x4 bb = *(const s16x4*)&biasTb[h * 4096 + j * 64 + i0];
        #pragma unroll
        for (int r = 0; r < 4; ++r)
          sP[(i0 + r) * 72 + j] = f2bf(fmaf(s2[n][r] * qs[r], ki, bf2f((u16)bb[r])));
      }
      // EN epilogue: transposed store
      const float wc = w4[h * 128 + onc + l15];
      #pragma unroll
      for (int m = 0; m < 4; ++m) {
        s16x4 u;
        u[0] = (short)f2bf(en[m][0] + wc); u[1] = (short)f2bf(en[m][1] + wc);
        u[2] = (short)f2bf(en[m][2] + wc); u[3] = (short)f2bf(en[m][3] + wc);
        *(s16x4*)&sENT[(onc + l15) * 72 + m * 16 + lk4] = u;
      }
    }
    __syncthreads();
  }

  // ---- tail: out += P_3 EN_3 ; + bias ; plain f32 store
  {
    #pragma unroll
    for (int ks = 0; ks < 2; ++ks) {
      const int koff = ks * 32 + lk8;
      bf16x8 a = *(const bf16x8*)&sP[(mt * 16 + l15) * 72 + koff];
      #pragma unroll
      for (int n = 0; n < 4; ++n) {
        bf16x8 bw = *(const bf16x8*)&sENT[(ch * 64 + n * 16 + l15) * 72 + koff];
        oacc[n] = MFMA(a, bw, oacc[n]);
      }
    }
    float* ob = out + ((size_t)blockIdx.x * 2 + w) * 8192;
    #pragma unroll
    for (int n = 0; n < 4; ++n) {
      const int col = ch * 64 + n * 16 + l15;
      const float bv = Ab[col];
      #pragma unroll
      for (int r = 0; r < 4; ++r)
        ob[(mt * 16 + lk4 + r) * 128 + col] = oacc[n][r] + bv;
    }
  }
}

// ---------------- host ----------------
extern "C" void kernel_launch(void* const* d_in, const int* in_sizes, int n_in,
                              void* d_out, int out_size, void* d_ws, size_t ws_size,
                              hipStream_t stream) {
  const float* E    = (const float*)d_in[0];
  const float* rpos = (const float*)d_in[1];
  const int*   ridx = (const int*)d_in[2];
  const float* Wq   = (const float*)d_in[3];
  const float* Qb   = (const float*)d_in[4];
  const float* Wk   = (const float*)d_in[5];
  const float* Wv   = (const float*)d_in[6];
  const float* Vb   = (const float*)d_in[7];
  const float* Wa   = (const float*)d_in[8];
  const float* Ab   = (const float*)d_in[9];
  const float* w1   = (const float*)d_in[10];
  const float* b1   = (const float*)d_in[11];
  const float* w2   = (const float*)d_in[12];
  const float* ls   = (const float*)d_in[13];

  char* ws = (char*)d_ws;
  u16* BigB    = (u16*)(ws + 0);         // 4*3*128*128*2 = 393216
  u16* NT      = (u16*)(ws + 393216);    // 4*128*128*2   = 131072
  u16* biasTb  = (u16*)(ws + 524288);    // 16384*2       = 32768
  float* augM  = (float*)(ws + 557056);  // 512*4
  float* augGq = (float*)(ws + 559104);  // 512*4
  float* w4    = (float*)(ws + 561152);  // 512*4
  float* cq4   = (float*)(ws + 563200);  // 16
  float* temp  = (float*)(ws + 563264);  // 16

  static bool attr_set = false;
  if (!attr_set) {
    hipFuncSetAttribute((const void*)k_msa,
                        hipFuncAttributeMaxDynamicSharedMemorySize, 129024);
    attr_set = true;
  }

  k_prep<<<17, 256, 0, stream>>>(Wq, Wk, Wv, Wa, Qb, Vb, rpos, w1, b1, w2,
                                 ls, ridx, BigB, NT, biasTb, augM, augGq,
                                 w4, cq4, temp);
  k_msa<<<512, 1024, 129024, stream>>>(E, BigB, NT, biasTb, augM, augGq, w4,
                                       cq4, temp, Ab, (float*)d_out);
}

// Round 9
// 149.704 us; speedup vs baseline: 1.5503x; 1.5503x over previous
//
#include <hip/hip_runtime.h>
#include <hip/hip_bf16.h>
#include <cstdint>

typedef uint16_t u16;
typedef _Float16 f16;
typedef __attribute__((ext_vector_type(8))) __bf16 bf16x8;
typedef __attribute__((ext_vector_type(4))) short s16x4;
typedef __attribute__((ext_vector_type(8))) short s16x8;
typedef __attribute__((ext_vector_type(4))) float f32x4;

#define MFMA(a, b, c) __builtin_amdgcn_mfma_f32_16x16x32_bf16((a), (b), (c), 0, 0, 0)
#define LOG100 4.6051701859880914f

__device__ __forceinline__ u16 f2bf(float f) {
  union { float f; uint32_t u; } v; v.f = f;
  uint32_t u = v.u;
  return (u16)((u + 0x7FFFu + ((u >> 16) & 1u)) >> 16);
}
__device__ __forceinline__ float bf2f(u16 s) {
  union { uint32_t u; float f; } v; v.u = ((uint32_t)s) << 16;
  return v.f;
}

union U8 { s16x8 s; bf16x8 b; };

__device__ __forceinline__ bf16x8 ld_bf8(const float* __restrict__ p) {
  float4 v0 = *(const float4*)p;
  float4 v1 = *(const float4*)(p + 4);
  U8 u;
  u.s[0] = (short)f2bf(v0.x); u.s[1] = (short)f2bf(v0.y);
  u.s[2] = (short)f2bf(v0.z); u.s[3] = (short)f2bf(v0.w);
  u.s[4] = (short)f2bf(v1.x); u.s[5] = (short)f2bf(v1.y);
  u.s[6] = (short)f2bf(v1.z); u.s[7] = (short)f2bf(v1.w);
  return u.b;
}
__device__ __forceinline__ bf16x8 zero_bf8() {
  U8 u;
  #pragma unroll
  for (int e = 0; e < 8; ++e) u.s[e] = 0;
  return u.b;
}

// ---------------- prep kernel: 17 blocks ----------------
__global__ __launch_bounds__(256) void k_prep(
    const float* __restrict__ Wq, const float* __restrict__ Wk,
    const float* __restrict__ Wv, const float* __restrict__ Wa,
    const float* __restrict__ Qb, const float* __restrict__ Vb,
    const float* __restrict__ rpos, const float* __restrict__ w1,
    const float* __restrict__ b1, const float* __restrict__ w2,
    const float* __restrict__ ls, const int* __restrict__ ridx,
    u16* __restrict__ BigB, u16* __restrict__ NTg, u16* __restrict__ biasTb,
    float* __restrict__ augM, float* __restrict__ augGq,
    float* __restrict__ w4, float* __restrict__ cq4, float* __restrict__ temp) {
  __shared__ float tbl[225][4];
  __shared__ __align__(16) u16 sWaT[128 * 200];
  const int bid = blockIdx.x;
  const int tid = threadIdx.x;

  if (bid == 16) {
    if (tid < 225) {
      float x0 = rpos[tid * 2 + 0], x1 = rpos[tid * 2 + 1];
      float a0 = 0.f, a1 = 0.f, a2 = 0.f, a3 = 0.f;
      for (int c = 0; c < 512; ++c) {
        float hv = fmaxf(fmaf(x0, w1[c], fmaf(x1, w1[512 + c], b1[c])), 0.f);
        a0 = fmaf(hv, w2[c * 4 + 0], a0);
        a1 = fmaf(hv, w2[c * 4 + 1], a1);
        a2 = fmaf(hv, w2[c * 4 + 2], a2);
        a3 = fmaf(hv, w2[c * 4 + 3], a3);
      }
      tbl[tid][0] = a0; tbl[tid][1] = a1; tbl[tid][2] = a2; tbl[tid][3] = a3;
    }
    if (tid < 4) temp[tid] = expf(fminf(ls[tid], LOG100));
    {
      int hh = tid >> 6, l = tid & 63;
      float s = 0.f;
      #pragma unroll
      for (int p = 0; p < 6; ++p) {
        float v = Qb[hh * 384 + l * 6 + p];
        s = fmaf(v, v, s);
      }
      s += __shfl_xor(s, 1); s += __shfl_xor(s, 2); s += __shfl_xor(s, 4);
      s += __shfl_xor(s, 8); s += __shfl_xor(s, 16); s += __shfl_xor(s, 32);
      if (l == 0) cq4[hh] = s;
    }
    __syncthreads();
    for (int it = 0; it < 64; ++it) {
      int gid = it * 256 + tid;
      int h = gid >> 12;
      int rem = gid & 4095;
      int q = rem >> 6, p = rem & 63;
      int ii = ((p >> 3) << 3) + (q >> 3);
      int jj = ((p & 7) << 3) + (q & 7);
      float v = tbl[ridx[ii * 64 + jj]][h];
      biasTb[gid] = f2bf(16.f / (1.f + expf(-v)));
    }
    return;
  }

  const int h = bid >> 2, t = bid & 3;
  const int wid = tid >> 6, lane = tid & 63;
  const int l15 = lane & 15, lk4 = (lane >> 4) << 2, lk8 = (lane >> 4) << 3;
  const f32x4 zf4 = {0.f, 0.f, 0.f, 0.f};

  f32x4 acc[2][8];
  #pragma unroll
  for (int mm = 0; mm < 2; ++mm)
    #pragma unroll
    for (int nn = 0; nn < 8; ++nn) acc[mm][nn] = zf4;

  if (t < 3) {
    const float* A = (t == 2) ? Wk : Wq;
    const float* B = (t == 0) ? Wk : ((t == 1) ? Wq : Wk);
    f32x4 accq[2] = {zf4, zf4};
    for (int ks = 0; ks < 12; ++ks) {
      const int koff = h * 384 + ks * 32 + lk8;
      bf16x8 a[2], bw[8];
      #pragma unroll
      for (int mm = 0; mm < 2; ++mm)
        a[mm] = ld_bf8(&A[(size_t)(wid * 32 + mm * 16 + l15) * 1536 + koff]);
      #pragma unroll
      for (int nn = 0; nn < 8; ++nn)
        bw[nn] = ld_bf8(&B[(size_t)(nn * 16 + l15) * 1536 + koff]);
      #pragma unroll
      for (int nn = 0; nn < 8; ++nn)
        #pragma unroll
        for (int mm = 0; mm < 2; ++mm)
          acc[mm][nn] = MFMA(a[mm], bw[nn], acc[mm][nn]);
      if (t >= 1) {
        bf16x8 bq = (l15 == 0) ? ld_bf8(&Qb[koff]) : zero_bf8();
        #pragma unroll
        for (int mm = 0; mm < 2; ++mm) accq[mm] = MFMA(a[mm], bq, accq[mm]);
      }
    }
    u16* dst = BigB + (size_t)((h * 3 + t) * 128) * 128;
    #pragma unroll
    for (int mm = 0; mm < 2; ++mm) {
      const int k0 = wid * 32 + mm * 16 + lk4;
      #pragma unroll
      for (int nn = 0; nn < 8; ++nn) {
        s16x4 u;
        u[0] = (short)f2bf(acc[mm][nn][0]); u[1] = (short)f2bf(acc[mm][nn][1]);
        u[2] = (short)f2bf(acc[mm][nn][2]); u[3] = (short)f2bf(acc[mm][nn][3]);
        *(s16x4*)&dst[(nn * 16 + l15) * 128 + k0] = u;
      }
    }
    if (t >= 1 && l15 == 0) {
      float* tgt = (t == 1) ? augGq : augM;
      const float sc = (t == 1) ? 2.f : 1.f;
      #pragma unroll
      for (int mm = 0; mm < 2; ++mm)
        #pragma unroll
        for (int r = 0; r < 4; ++r)
          tgt[h * 128 + wid * 32 + mm * 16 + lk4 + r] = sc * accq[mm][r];
    }
  } else {
    f32x4 accv[8];
    #pragma unroll
    for (int nn = 0; nn < 8; ++nn) accv[nn] = zf4;
    for (int chunk = 0; chunk < 2; ++chunk) {
      __syncthreads();
      for (int it = 0; it < 24; ++it) {
        int idx = it * 256 + tid;
        int a = idx >> 5;
        int c4 = (idx & 31) << 2;
        const float4 v = *(const float4*)&Wa[(size_t)(h * 384 + chunk * 192 + a) * 128 + c4];
        sWaT[(c4 + 0) * 200 + a] = f2bf(v.x);
        sWaT[(c4 + 1) * 200 + a] = f2bf(v.y);
        sWaT[(c4 + 2) * 200 + a] = f2bf(v.z);
        sWaT[(c4 + 3) * 200 + a] = f2bf(v.w);
      }
      __syncthreads();
      for (int ks2 = 0; ks2 < 6; ++ks2) {
        const int koff = h * 384 + chunk * 192 + ks2 * 32 + lk8;
        const int lkoff = ks2 * 32 + lk8;
        bf16x8 a[2], bw[8];
        #pragma unroll
        for (int mm = 0; mm < 2; ++mm)
          a[mm] = ld_bf8(&Wv[(size_t)(wid * 32 + mm * 16 + l15) * 1536 + koff]);
        #pragma unroll
        for (int nn = 0; nn < 8; ++nn)
          bw[nn] = *(const bf16x8*)&sWaT[(nn * 16 + l15) * 200 + lkoff];
        #pragma unroll
        for (int nn = 0; nn < 8; ++nn)
          #pragma unroll
          for (int mm = 0; mm < 2; ++mm)
            acc[mm][nn] = MFMA(a[mm], bw[nn], acc[mm][nn]);
        if (wid == 0) {
          bf16x8 av = (l15 == 0) ? ld_bf8(&Vb[koff]) : zero_bf8();
          #pragma unroll
          for (int nn = 0; nn < 8; ++nn) accv[nn] = MFMA(av, bw[nn], accv[nn]);
        }
      }
    }
    u16* dst = NTg + (size_t)(h * 128) * 128;
    #pragma unroll
    for (int mm = 0; mm < 2; ++mm) {
      const int k0 = wid * 32 + mm * 16 + lk4;
      #pragma unroll
      for (int nn = 0; nn < 8; ++nn) {
        s16x4 u;
        u[0] = (short)f2bf(acc[mm][nn][0]); u[1] = (short)f2bf(acc[mm][nn][1]);
        u[2] = (short)f2bf(acc[mm][nn][2]); u[3] = (short)f2bf(acc[mm][nn][3]);
        *(s16x4*)&dst[(nn * 16 + l15) * 128 + k0] = u;
      }
    }
    if (wid == 0 && lane < 16) {
      #pragma unroll
      for (int nn = 0; nn < 8; ++nn)
        w4[h * 128 + nn * 16 + lane] = accv[nn][0];
    }
  }
}

// ---------------- norm kernel ----------------
// grid 256, 512 thr (8 waves). Block = 4 windows, all heads.
__global__ __launch_bounds__(512, 1) void k_norm(
    const float* __restrict__ E, const u16* __restrict__ BigB,
    const float* __restrict__ augGq, const float* __restrict__ cq4,
    const float* __restrict__ temp, f16* __restrict__ norms) {
  extern __shared__ __align__(16) char lds[];
  u16* sE4 = (u16*)lds;                 // 4 x [64][136] = 69632 B
  u16* sG = (u16*)(lds + 69632);        // [256][136]    = 69632 B
  float* sDp = (float*)(lds + 139264);  // [2][8][64]    = 4096 B

  const int tid = threadIdx.x;
  const int wv = tid >> 6, lane = tid & 63;
  const int l15 = lane & 15, lk4 = (lane >> 4) << 2, lk8 = (lane >> 4) << 3;
  const int rw = (wv & 3) * 32;
  const int b0 = blockIdx.x * 4;
  const f32x4 zf4 = {0.f, 0.f, 0.f, 0.f};

  // stage E for 4 windows
  {
    const float4* E4 = (const float4*)(E + (size_t)b0 * 8192);
    #pragma unroll
    for (int it = 0; it < 16; ++it) {
      int i = tid + it * 512;
      float4 v = E4[i];
      int ww = i >> 11, idx = i & 2047;
      int row = idx >> 5, c = (idx & 31) << 2;
      s16x4 u;
      u[0] = (short)f2bf(v.x); u[1] = (short)f2bf(v.y);
      u[2] = (short)f2bf(v.z); u[3] = (short)f2bf(v.w);
      *(s16x4*)&sE4[ww * 8704 + row * 136 + c] = u;
    }
  }

  for (int h = 0; h < 4; ++h) {
    __syncthreads();
    // stage Gq_h + Gk_h: 256 rows x 128
    {
      const u16* src = BigB + (size_t)(h * 3 + 1) * 16384;
      #pragma unroll
      for (int q = 0; q < 8; ++q) {
        int off = (q * 512 + tid) * 8;
        int r = off >> 7, c = off & 127;
        *(s16x8*)&sG[r * 136 + c] = *(const s16x8*)&src[off];
      }
    }
    const float th = temp[h], cqh = cq4[h];
    float aq[2][4];
    #pragma unroll
    for (int mm = 0; mm < 2; ++mm)
      #pragma unroll
      for (int r = 0; r < 4; ++r)
        aq[mm][r] = (wv < 4) ? augGq[h * 128 + rw + mm * 16 + lk4 + r] : 0.f;
    __syncthreads();

    for (int wi = 0; wi < 4; ++wi) {
      const u16* sE = &sE4[wi * 8704];
      const u16* Gw = &sG[(((wv < 4) ? 0 : 128) + rw) * 136];
      f32x4 z[2][4];
      #pragma unroll
      for (int mm = 0; mm < 2; ++mm)
        #pragma unroll
        for (int n = 0; n < 4; ++n) z[mm][n] = zf4;
      #pragma unroll
      for (int ks = 0; ks < 4; ++ks) {
        const int koff = ks * 32 + lk8;
        bf16x8 a0 = *(const bf16x8*)&Gw[l15 * 136 + koff];
        bf16x8 a1 = *(const bf16x8*)&Gw[(16 + l15) * 136 + koff];
        #pragma unroll
        for (int n = 0; n < 4; ++n) {
          bf16x8 bw = *(const bf16x8*)&sE[(n * 16 + l15) * 136 + koff];
          z[0][n] = MFMA(a0, bw, z[0][n]);
          z[1][n] = MFMA(a1, bw, z[1][n]);
        }
      }
      #pragma unroll
      for (int n = 0; n < 4; ++n) {
        const int j = n * 16 + l15;
        float p = 0.f;
        #pragma unroll
        for (int mm = 0; mm < 2; ++mm)
          #pragma unroll
          for (int r = 0; r < 4; ++r)
            p = fmaf(z[mm][n][r] + aq[mm][r],
                     bf2f(sE[j * 136 + rw + mm * 16 + lk4 + r]), p);
        p += __shfl_xor(p, 16);
        p += __shfl_xor(p, 32);
        if (lane < 16) sDp[((wi & 1) * 8 + wv) * 64 + j] = p;
      }
      // finalize previous window (other buffer)
      if (wi > 0 && tid < 128) {
        const int pw = wi - 1;
        const float* bp = &sDp[((pw & 1) * 8) * 64];
        const int j = tid & 63;
        const size_t o = ((size_t)(b0 + pw) * 4 + h) * 128;
        if (tid < 64) {
          float dq = bp[j] + bp[64 + j] + bp[128 + j] + bp[192 + j];
          float qs = th / fmaxf(sqrtf(fmaxf(dq + cqh, 0.f)), 1e-12f);
          norms[o + j] = (f16)qs;
        } else {
          float dk = bp[256 + j] + bp[320 + j] + bp[384 + j] + bp[448 + j];
          float ki = 1.f / fmaxf(sqrtf(fmaxf(dk, 0.f)), 1e-12f);
          norms[o + 64 + j] = (f16)ki;
        }
      }
      __syncthreads();
    }
    // finalize window 3 (buffer 1)
    if (tid < 128) {
      const float* bp = &sDp[8 * 64];
      const int j = tid & 63;
      const size_t o = ((size_t)(b0 + 3) * 4 + h) * 128;
      if (tid < 64) {
        float dq = bp[j] + bp[64 + j] + bp[128 + j] + bp[192 + j];
        float qs = th / fmaxf(sqrtf(fmaxf(dq + cqh, 0.f)), 1e-12f);
        norms[o + j] = (f16)qs;
      } else {
        float dk = bp[256 + j] + bp[320 + j] + bp[384 + j] + bp[448 + j];
        float ki = 1.f / fmaxf(sqrtf(fmaxf(dk, 0.f)), 1e-12f);
        norms[o + 64 + j] = (f16)ki;
      }
    }
  }
}

// ---------------- main fused kernel ----------------
// 1 block = 2 windows, 1024 thr = 16 waves. One shared weight buffer sW
// time-multiplexed: M_h during T1 phase, NT_h during EN phase. Reg staging
// (issue-early / commit-after-barrier) hides the global load latency.
// Per head: [commit M_h; PV] |A| [issue NT_h; T1] |B| [commit NT_h; S]
//           |C| [issue M_{h+1}; EN; P/EN epilogues] |D|
__global__ __launch_bounds__(1024, 1) void k_msa(
    const float* __restrict__ E, const u16* __restrict__ BigB,
    const u16* __restrict__ NTg, const u16* __restrict__ biasTb,
    const float* __restrict__ augM, const float* __restrict__ w4,
    const f16* __restrict__ norms, const float* __restrict__ Ab,
    float* __restrict__ out) {
  extern __shared__ __align__(16) char lds[];
  u16* sEb   = (u16*)(lds);               // 2 x [64][136]  = 34816 B
  u16* sW    = (u16*)(lds + 34816);       // [128][136]     = 34816 B
  u16* sT1b  = (u16*)(lds + 69632);       // 2 x [64][136]  = 34816 B
  u16* sPb   = (u16*)(lds + 104448);      // 2 x [64][72]   = 18432 B
  u16* sENTb = (u16*)(lds + 122880);      // 2 x [128][72]  = 36864 B
  // total 159744 B

  const int tid = threadIdx.x;
  const int wid = tid >> 6;
  const int w = wid >> 3;
  const int wv = wid & 7;
  const int lane = tid & 63;
  const int l15 = lane & 15;
  const int lk4 = (lane >> 4) << 2;
  const int lk8 = (lane >> 4) << 3;
  const int mt = wv >> 1;
  const int ch = wv & 1;
  const int j0 = ch * 32;
  const int onc = wv << 4;
  const size_t b = (size_t)blockIdx.x * 2 + w;

  u16* sE = sEb + w * 8704;
  u16* sT1 = sT1b + w * 8704;
  u16* sP = sPb + w * 4608;
  u16* sENT = sENTb + w * 9216;

  // ---- prologue: stage E (both windows) + M_0 (direct to sW)
  {
    const float4* E4 = (const float4*)(E + (size_t)blockIdx.x * 16384);
    #pragma unroll
    for (int it = 0; it < 4; ++it) {
      int i = tid + it * 1024;
      float4 v = E4[i];
      int ww = i >> 11, idx = i & 2047;
      int row = idx >> 5, c = (idx & 31) << 2;
      s16x4 u;
      u[0] = (short)f2bf(v.x); u[1] = (short)f2bf(v.y);
      u[2] = (short)f2bf(v.z); u[3] = (short)f2bf(v.w);
      *(s16x4*)&sEb[ww * 8704 + row * 136 + c] = u;
    }
    #pragma unroll
    for (int q = 0; q < 2; ++q) {
      int off = (q * 1024 + tid) * 8;
      int r = off >> 7, c = off & 127;
      *(s16x8*)&sW[r * 136 + c] = *(const s16x8*)&BigB[off];
    }
  }
  __syncthreads();

  const f32x4 zf4 = {0.f, 0.f, 0.f, 0.f};
  f32x4 oacc[4] = {zf4, zf4, zf4, zf4};
  s16x8 mr0, mr1, nr0, nr1;
  const int stg_r = tid >> 3;
  const int stg_c = (tid & 7) * 16;

  for (int h = 0; h < 4; ++h) {
    // ===== segment D(h-1)..A: commit M_h ; PV =====
    if (h > 0) {
      *(s16x8*)&sW[stg_r * 136 + stg_c] = mr0;
      *(s16x8*)&sW[stg_r * 136 + stg_c + 8] = mr1;
      // PV: out += P_{h-1} @ EN_{h-1}
      #pragma unroll
      for (int ks = 0; ks < 2; ++ks) {
        const int koff = ks * 32 + lk8;
        bf16x8 a = *(const bf16x8*)&sP[(mt * 16 + l15) * 72 + koff];
        #pragma unroll
        for (int n = 0; n < 4; ++n) {
          bf16x8 bw = *(const bf16x8*)&sENT[(ch * 64 + n * 16 + l15) * 72 + koff];
          oacc[n] = MFMA(a, bw, oacc[n]);
        }
      }
    }
    __syncthreads();  // A: M_h committed & visible
    // ===== segment A..B: issue NT_h ; T1 = E M_h^T + augM =====
    {
      const u16* src = NTg + (size_t)h * 16384;
      nr0 = *(const s16x8*)&src[tid * 16];
      nr1 = *(const s16x8*)&src[tid * 16 + 8];
    }
    {
      f32x4 t1[4] = {zf4, zf4, zf4, zf4};
      #pragma unroll
      for (int ks = 0; ks < 4; ++ks) {
        const int koff = ks * 32 + lk8;
        bf16x8 bw = *(const bf16x8*)&sW[(onc + l15) * 136 + koff];
        #pragma unroll
        for (int m = 0; m < 4; ++m) {
          bf16x8 a = *(const bf16x8*)&sE[(m * 16 + l15) * 136 + koff];
          t1[m] = MFMA(a, bw, t1[m]);
        }
      }
      const float ta = augM[h * 128 + onc + l15];
      const int col = onc + l15;
      #pragma unroll
      for (int m = 0; m < 4; ++m)
        #pragma unroll
        for (int r = 0; r < 4; ++r)
          sT1[(m * 16 + lk4 + r) * 136 + col] = f2bf(t1[m][r] + ta);
    }
    __syncthreads();  // B: T1 done; sW reads (M_h) done
    // ===== segment B..C: commit NT_h ; S = T1 E^T =====
    *(s16x8*)&sW[stg_r * 136 + stg_c] = nr0;
    *(s16x8*)&sW[stg_r * 136 + stg_c + 8] = nr1;
    f32x4 s2[2] = {zf4, zf4};
    #pragma unroll
    for (int ks = 0; ks < 4; ++ks) {
      const int koff = ks * 32 + lk8;
      bf16x8 a = *(const bf16x8*)&sT1[(mt * 16 + l15) * 136 + koff];
      #pragma unroll
      for (int n = 0; n < 2; ++n) {
        bf16x8 bw = *(const bf16x8*)&sE[(j0 + n * 16 + l15) * 136 + koff];
        s2[n] = MFMA(a, bw, s2[n]);
      }
    }
    __syncthreads();  // C: NT_h committed & visible
    // ===== segment C..D: issue M_{h+1} ; EN = E NT_h + w4 ; epilogues =====
    if (h < 3) {
      const u16* src = BigB + (size_t)(h + 1) * 49152;
      mr0 = *(const s16x8*)&src[tid * 16];
      mr1 = *(const s16x8*)&src[tid * 16 + 8];
    }
    {
      f32x4 en[4] = {zf4, zf4, zf4, zf4};
      #pragma unroll
      for (int ks = 0; ks < 4; ++ks) {
        const int koff = ks * 32 + lk8;
        bf16x8 bw = *(const bf16x8*)&sW[(onc + l15) * 136 + koff];
        #pragma unroll
        for (int m = 0; m < 4; ++m) {
          bf16x8 a = *(const bf16x8*)&sE[(m * 16 + l15) * 136 + koff];
          en[m] = MFMA(a, bw, en[m]);
        }
      }
      // P epilogue (norms precomputed; qs includes temp)
      const f16* nrm = norms + (((size_t)b * 4 + h) << 7);
      const int i0 = mt * 16 + lk4;
      float qs[4];
      #pragma unroll
      for (int r = 0; r < 4; ++r) qs[r] = (float)nrm[i0 + r];
      #pragma unroll
      for (int n = 0; n < 2; ++n) {
        const int j = j0 + n * 16 + l15;
        const float ki = (float)nrm[64 + j];
        s16x4 bb = *(const s16x4*)&biasTb[h * 4096 + j * 64 + i0];
        #pragma unroll
        for (int r = 0; r < 4; ++r)
          sP[(i0 + r) * 72 + j] = f2bf(fmaf(s2[n][r] * qs[r], ki, bf2f((u16)bb[r])));
      }
      // EN epilogue: transposed store
      const float wc = w4[h * 128 + onc + l15];
      #pragma unroll
      for (int m = 0; m < 4; ++m) {
        s16x4 u;
        u[0] = (short)f2bf(en[m][0] + wc); u[1] = (short)f2bf(en[m][1] + wc);
        u[2] = (short)f2bf(en[m][2] + wc); u[3] = (short)f2bf(en[m][3] + wc);
        *(s16x4*)&sENT[(onc + l15) * 72 + m * 16 + lk4] = u;
      }
    }
    __syncthreads();  // D: sP/sENT visible; sW reads (NT_h) done
  }

  // ---- tail: out += P_3 EN_3 ; + bias ; f32 store
  {
    #pragma unroll
    for (int ks = 0; ks < 2; ++ks) {
      const int koff = ks * 32 + lk8;
      bf16x8 a = *(const bf16x8*)&sP[(mt * 16 + l15) * 72 + koff];
      #pragma unroll
      for (int n = 0; n < 4; ++n) {
        bf16x8 bw = *(const bf16x8*)&sENT[(ch * 64 + n * 16 + l15) * 72 + koff];
        oacc[n] = MFMA(a, bw, oacc[n]);
      }
    }
    float* ob = out + b * 8192;
    #pragma unroll
    for (int n = 0; n < 4; ++n) {
      const int col = ch * 64 + n * 16 + l15;
      const float bv = Ab[col];
      #pragma unroll
      for (int r = 0; r < 4; ++r)
        ob[(mt * 16 + lk4 + r) * 128 + col] = oacc[n][r] + bv;
    }
  }
}

// ---------------- host ----------------
extern "C" void kernel_launch(void* const* d_in, const int* in_sizes, int n_in,
                              void* d_out, int out_size, void* d_ws, size_t ws_size,
                              hipStream_t stream) {
  const float* E    = (const float*)d_in[0];
  const float* rpos = (const float*)d_in[1];
  const int*   ridx = (const int*)d_in[2];
  const float* Wq   = (const float*)d_in[3];
  const float* Qb   = (const float*)d_in[4];
  const float* Wk   = (const float*)d_in[5];
  const float* Wv   = (const float*)d_in[6];
  const float* Vb   = (const float*)d_in[7];
  const float* Wa   = (const float*)d_in[8];
  const float* Ab   = (const float*)d_in[9];
  const float* w1   = (const float*)d_in[10];
  const float* b1   = (const float*)d_in[11];
  const float* w2   = (const float*)d_in[12];
  const float* ls   = (const float*)d_in[13];

  char* ws = (char*)d_ws;
  u16* BigB    = (u16*)(ws + 0);         // 4*3*128*128*2 = 393216
  u16* NTg     = (u16*)(ws + 393216);    // 4*128*128*2   = 131072
  u16* biasTb  = (u16*)(ws + 524288);    // 32768
  float* augM  = (float*)(ws + 557056);  // 2048
  float* augGq = (float*)(ws + 559104);  // 2048
  float* w4    = (float*)(ws + 561152);  // 2048
  float* cq4   = (float*)(ws + 563200);  // 64
  float* temp  = (float*)(ws + 563264);  // 64
  f16* norms   = (f16*)(ws + 563328);    // 1024*4*128*2 = 1048576

  hipFuncSetAttribute((const void*)k_msa,
                      hipFuncAttributeMaxDynamicSharedMemorySize, 159744);
  hipFuncSetAttribute((const void*)k_norm,
                      hipFuncAttributeMaxDynamicSharedMemorySize, 143360);

  k_prep<<<17, 256, 0, stream>>>(Wq, Wk, Wv, Wa, Qb, Vb, rpos, w1, b1, w2,
                                 ls, ridx, BigB, NTg, biasTb, augM, augGq,
                                 w4, cq4, temp);
  k_norm<<<256, 512, 143360, stream>>>(E, BigB, augGq, cq4, temp, norms);
  k_msa<<<512, 1024, 159744, stream>>>(E, BigB, NTg, biasTb, augM, w4,
                                       norms, Ab, (float*)d_out);
}

// Round 10
// 134.832 us; speedup vs baseline: 1.7213x; 1.1103x over previous
//
#include <hip/hip_runtime.h>
#include <hip/hip_bf16.h>
#include <cstdint>

typedef uint16_t u16;
typedef _Float16 f16;
typedef __attribute__((ext_vector_type(8))) __bf16 bf16x8;
typedef __attribute__((ext_vector_type(4))) short s16x4;
typedef __attribute__((ext_vector_type(8))) short s16x8;
typedef __attribute__((ext_vector_type(4))) float f32x4;

#define MFMA(a, b, c) __builtin_amdgcn_mfma_f32_16x16x32_bf16((a), (b), (c), 0, 0, 0)
#define LOG100 4.6051701859880914f

__device__ __forceinline__ u16 f2bf(float f) {
  union { float f; uint32_t u; } v; v.f = f;
  uint32_t u = v.u;
  return (u16)((u + 0x7FFFu + ((u >> 16) & 1u)) >> 16);
}
__device__ __forceinline__ float bf2f(u16 s) {
  union { uint32_t u; float f; } v; v.u = ((uint32_t)s) << 16;
  return v.f;
}

union U8 { s16x8 s; bf16x8 b; };

__device__ __forceinline__ bf16x8 ld_bf8(const float* __restrict__ p) {
  float4 v0 = *(const float4*)p;
  float4 v1 = *(const float4*)(p + 4);
  U8 u;
  u.s[0] = (short)f2bf(v0.x); u.s[1] = (short)f2bf(v0.y);
  u.s[2] = (short)f2bf(v0.z); u.s[3] = (short)f2bf(v0.w);
  u.s[4] = (short)f2bf(v1.x); u.s[5] = (short)f2bf(v1.y);
  u.s[6] = (short)f2bf(v1.z); u.s[7] = (short)f2bf(v1.w);
  return u.b;
}
__device__ __forceinline__ bf16x8 zero_bf8() {
  U8 u;
  #pragma unroll
  for (int e = 0; e < 8; ++e) u.s[e] = 0;
  return u.b;
}

// ---------------- prep kernel: 17 blocks x 512 thr, LDS-staged panels ----------
// blocks 0..15 = (h, t):
//  t=0: M  = Wq_h Wk_h^T -> BigB[(h*3+0)*128 + l][e]          (A=Wq, B=Wk)
//  t=1: Gq = Wq Wq^T     -> BigB[(h*3+1)*128 + l][e]; augGq   (A=B=Wq, alias)
//  t=2: Gk = Wk Wk^T     -> BigB[(h*3+2)*128 + l][e]; augM    (A=B=Wk, alias)
//  t=3: N  = Wv_h Wa_h   -> NTg[h*128 + c][a]; w4             (A=Wv, B=Wa^T)
// block 16: bias table (bf16) + temp + cq4
__global__ __launch_bounds__(512) void k_prep(
    const float* __restrict__ Wq, const float* __restrict__ Wk,
    const float* __restrict__ Wv, const float* __restrict__ Wa,
    const float* __restrict__ Qb, const float* __restrict__ Vb,
    const float* __restrict__ rpos, const float* __restrict__ w1,
    const float* __restrict__ b1, const float* __restrict__ w2,
    const float* __restrict__ ls, const int* __restrict__ ridx,
    u16* __restrict__ BigB, u16* __restrict__ NTg, u16* __restrict__ biasTb,
    float* __restrict__ augM, float* __restrict__ augGq,
    float* __restrict__ w4, float* __restrict__ cq4, float* __restrict__ temp) {
  extern __shared__ __align__(16) char lds[];
  const int bid = blockIdx.x;
  const int tid = threadIdx.x;

  if (bid == 16) {
    float (*tbl)[4] = (float(*)[4])lds;        // [225][4]
    if (tid < 225) {
      float x0 = rpos[tid * 2 + 0], x1 = rpos[tid * 2 + 1];
      float a0 = 0.f, a1 = 0.f, a2 = 0.f, a3 = 0.f;
      for (int c = 0; c < 512; ++c) {
        float hv = fmaxf(fmaf(x0, w1[c], fmaf(x1, w1[512 + c], b1[c])), 0.f);
        a0 = fmaf(hv, w2[c * 4 + 0], a0);
        a1 = fmaf(hv, w2[c * 4 + 1], a1);
        a2 = fmaf(hv, w2[c * 4 + 2], a2);
        a3 = fmaf(hv, w2[c * 4 + 3], a3);
      }
      tbl[tid][0] = a0; tbl[tid][1] = a1; tbl[tid][2] = a2; tbl[tid][3] = a3;
    }
    if (tid < 4) temp[tid] = expf(fminf(ls[tid], LOG100));
    if (tid < 256) {
      int hh = tid >> 6, l = tid & 63;
      float s = 0.f;
      #pragma unroll
      for (int p = 0; p < 6; ++p) {
        float v = Qb[hh * 384 + l * 6 + p];
        s = fmaf(v, v, s);
      }
      s += __shfl_xor(s, 1); s += __shfl_xor(s, 2); s += __shfl_xor(s, 4);
      s += __shfl_xor(s, 8); s += __shfl_xor(s, 16); s += __shfl_xor(s, 32);
      if (l == 0) cq4[hh] = s;
    }
    __syncthreads();
    for (int it = 0; it < 32; ++it) {
      int gid = it * 512 + tid;
      int h = gid >> 12;
      int rem = gid & 4095;
      int q = rem >> 6, p = rem & 63;
      int ii = ((p >> 3) << 3) + (q >> 3);
      int jj = ((p & 7) << 3) + (q & 7);
      float v = tbl[ridx[ii * 64 + jj]][h];
      biasTb[gid] = f2bf(16.f / (1.f + expf(-v)));
    }
    return;
  }

  u16* sA = (u16*)lds;                 // [128][200] bf16 = 51200 B
  u16* sB = (u16*)(lds + 51200);       // [128][200] bf16 = 51200 B

  const int h = bid >> 2, t = bid & 3;
  const int wid = tid >> 6, lane = tid & 63;
  const int l15 = lane & 15, lk4 = (lane >> 4) << 2, lk8 = (lane >> 4) << 3;
  const f32x4 zf4 = {0.f, 0.f, 0.f, 0.f};

  const float* Asrc = (t == 2) ? Wk : ((t == 3) ? Wv : Wq);
  const u16* sBr = (t == 1 || t == 2) ? sA : sB;  // Gram blocks alias B=A
  const bool haveQ = (t == 1 || t == 2);
  const float sc = (t == 1) ? 2.f : 1.f;

  f32x4 acc[8], accq[8], accv;
  #pragma unroll
  for (int m = 0; m < 8; ++m) { acc[m] = zf4; accq[m] = zf4; }
  accv = zf4;

  for (int chunk = 0; chunk < 2; ++chunk) {
    const int gbase = h * 384 + chunk * 192;
    __syncthreads();   // previous chunk's LDS reads done
    // ---- stage A panel [128 rows e][192 cols f], coalesced
    for (int it = 0; it < 12; ++it) {
      int idx = it * 512 + tid;                // 6144 float4
      int row = idx / 48;
      int c4 = (idx - row * 48) * 4;
      float4 v = *(const float4*)&Asrc[(size_t)row * 1536 + gbase + c4];
      s16x4 u;
      u[0] = (short)f2bf(v.x); u[1] = (short)f2bf(v.y);
      u[2] = (short)f2bf(v.z); u[3] = (short)f2bf(v.w);
      *(s16x4*)&sA[row * 200 + c4] = u;
    }
    // ---- stage B panel
    if (t == 0) {          // B = Wk, same layout as A
      for (int it = 0; it < 12; ++it) {
        int idx = it * 512 + tid;
        int row = idx / 48;
        int c4 = (idx - row * 48) * 4;
        float4 v = *(const float4*)&Wk[(size_t)row * 1536 + gbase + c4];
        s16x4 u;
        u[0] = (short)f2bf(v.x); u[1] = (short)f2bf(v.y);
        u[2] = (short)f2bf(v.z); u[3] = (short)f2bf(v.w);
        *(s16x4*)&sB[row * 200 + c4] = u;
      }
    } else if (t == 3) {   // B = Wa^T: coalesced read, transposed LDS write
      for (int it = 0; it < 12; ++it) {
        int idx = it * 512 + tid;                // 6144 float4
        int a = idx >> 5;                        // 0..191
        int c4 = (idx & 31) << 2;                // 0..124
        float4 v = *(const float4*)&Wa[(size_t)(gbase + a) * 128 + c4];
        sB[(c4 + 0) * 200 + a] = f2bf(v.x);
        sB[(c4 + 1) * 200 + a] = f2bf(v.y);
        sB[(c4 + 2) * 200 + a] = f2bf(v.z);
        sB[(c4 + 3) * 200 + a] = f2bf(v.w);
      }
    }
    __syncthreads();
    // ---- MFMA from LDS: wave wid owns B-tile wid; all 8 A-tiles
    #pragma unroll
    for (int ks = 0; ks < 6; ++ks) {
      const int koff = ks * 32 + lk8;
      bf16x8 bw = *(const bf16x8*)&sBr[(wid * 16 + l15) * 200 + koff];
      bf16x8 a[8];
      #pragma unroll
      for (int m = 0; m < 8; ++m)
        a[m] = *(const bf16x8*)&sA[(m * 16 + l15) * 200 + koff];
      #pragma unroll
      for (int m = 0; m < 8; ++m)
        acc[m] = MFMA(a[m], bw, acc[m]);
      if (haveQ && wid == 0) {
        bf16x8 bq = (l15 == 0) ? ld_bf8(&Qb[gbase + ks * 32 + lk8]) : zero_bf8();
        #pragma unroll
        for (int m = 0; m < 8; ++m)
          accq[m] = MFMA(a[m], bq, accq[m]);
      }
      if (t == 3) {
        bf16x8 av = (l15 == 0) ? ld_bf8(&Vb[gbase + ks * 32 + lk8]) : zero_bf8();
        accv = MFMA(av, bw, accv);
      }
    }
  }

  // ---- stores
  u16* dst = (t < 3) ? (BigB + (size_t)(h * 3 + t) * 16384)
                     : (NTg + (size_t)h * 16384);
  #pragma unroll
  for (int m = 0; m < 8; ++m) {
    s16x4 u;
    u[0] = (short)f2bf(acc[m][0]); u[1] = (short)f2bf(acc[m][1]);
    u[2] = (short)f2bf(acc[m][2]); u[3] = (short)f2bf(acc[m][3]);
    *(s16x4*)&dst[(wid * 16 + l15) * 128 + m * 16 + lk4] = u;
  }
  if (haveQ && wid == 0 && l15 == 0) {
    float* tgt = (t == 1) ? augGq : augM;
    #pragma unroll
    for (int m = 0; m < 8; ++m)
      #pragma unroll
      for (int r = 0; r < 4; ++r)
        tgt[h * 128 + m * 16 + lk4 + r] = sc * accq[m][r];
  }
  if (t == 3 && lane < 16)
    w4[h * 128 + wid * 16 + lane] = accv[0];
}

// ---------------- norm kernel (unchanged from round 9) ----------------
__global__ __launch_bounds__(512, 1) void k_norm(
    const float* __restrict__ E, const u16* __restrict__ BigB,
    const float* __restrict__ augGq, const float* __restrict__ cq4,
    const float* __restrict__ temp, f16* __restrict__ norms) {
  extern __shared__ __align__(16) char lds[];
  u16* sE4 = (u16*)lds;                 // 4 x [64][136] = 69632 B
  u16* sG = (u16*)(lds + 69632);        // [256][136]    = 69632 B
  float* sDp = (float*)(lds + 139264);  // [2][8][64]    = 4096 B

  const int tid = threadIdx.x;
  const int wv = tid >> 6, lane = tid & 63;
  const int l15 = lane & 15, lk4 = (lane >> 4) << 2, lk8 = (lane >> 4) << 3;
  const int rw = (wv & 3) * 32;
  const int b0 = blockIdx.x * 4;
  const f32x4 zf4 = {0.f, 0.f, 0.f, 0.f};

  {
    const float4* E4 = (const float4*)(E + (size_t)b0 * 8192);
    #pragma unroll
    for (int it = 0; it < 16; ++it) {
      int i = tid + it * 512;
      float4 v = E4[i];
      int ww = i >> 11, idx = i & 2047;
      int row = idx >> 5, c = (idx & 31) << 2;
      s16x4 u;
      u[0] = (short)f2bf(v.x); u[1] = (short)f2bf(v.y);
      u[2] = (short)f2bf(v.z); u[3] = (short)f2bf(v.w);
      *(s16x4*)&sE4[ww * 8704 + row * 136 + c] = u;
    }
  }

  for (int h = 0; h < 4; ++h) {
    __syncthreads();
    {
      const u16* src = BigB + (size_t)(h * 3 + 1) * 16384;
      #pragma unroll
      for (int q = 0; q < 8; ++q) {
        int off = (q * 512 + tid) * 8;
        int r = off >> 7, c = off & 127;
        *(s16x8*)&sG[r * 136 + c] = *(const s16x8*)&src[off];
      }
    }
    const float th = temp[h], cqh = cq4[h];
    float aq[2][4];
    #pragma unroll
    for (int mm = 0; mm < 2; ++mm)
      #pragma unroll
      for (int r = 0; r < 4; ++r)
        aq[mm][r] = (wv < 4) ? augGq[h * 128 + rw + mm * 16 + lk4 + r] : 0.f;
    __syncthreads();

    for (int wi = 0; wi < 4; ++wi) {
      const u16* sE = &sE4[wi * 8704];
      const u16* Gw = &sG[(((wv < 4) ? 0 : 128) + rw) * 136];
      f32x4 z[2][4];
      #pragma unroll
      for (int mm = 0; mm < 2; ++mm)
        #pragma unroll
        for (int n = 0; n < 4; ++n) z[mm][n] = zf4;
      #pragma unroll
      for (int ks = 0; ks < 4; ++ks) {
        const int koff = ks * 32 + lk8;
        bf16x8 a0 = *(const bf16x8*)&Gw[l15 * 136 + koff];
        bf16x8 a1 = *(const bf16x8*)&Gw[(16 + l15) * 136 + koff];
        #pragma unroll
        for (int n = 0; n < 4; ++n) {
          bf16x8 bw = *(const bf16x8*)&sE[(n * 16 + l15) * 136 + koff];
          z[0][n] = MFMA(a0, bw, z[0][n]);
          z[1][n] = MFMA(a1, bw, z[1][n]);
        }
      }
      #pragma unroll
      for (int n = 0; n < 4; ++n) {
        const int j = n * 16 + l15;
        float p = 0.f;
        #pragma unroll
        for (int mm = 0; mm < 2; ++mm)
          #pragma unroll
          for (int r = 0; r < 4; ++r)
            p = fmaf(z[mm][n][r] + aq[mm][r],
                     bf2f(sE[j * 136 + rw + mm * 16 + lk4 + r]), p);
        p += __shfl_xor(p, 16);
        p += __shfl_xor(p, 32);
        if (lane < 16) sDp[((wi & 1) * 8 + wv) * 64 + j] = p;
      }
      if (wi > 0 && tid < 128) {
        const int pw = wi - 1;
        const float* bp = &sDp[((pw & 1) * 8) * 64];
        const int j = tid & 63;
        const size_t o = ((size_t)(b0 + pw) * 4 + h) * 128;
        if (tid < 64) {
          float dq = bp[j] + bp[64 + j] + bp[128 + j] + bp[192 + j];
          float qs = th / fmaxf(sqrtf(fmaxf(dq + cqh, 0.f)), 1e-12f);
          norms[o + j] = (f16)qs;
        } else {
          float dk = bp[256 + j] + bp[320 + j] + bp[384 + j] + bp[448 + j];
          float ki = 1.f / fmaxf(sqrtf(fmaxf(dk, 0.f)), 1e-12f);
          norms[o + 64 + j] = (f16)ki;
        }
      }
      __syncthreads();
    }
    if (tid < 128) {
      const float* bp = &sDp[8 * 64];
      const int j = tid & 63;
      const size_t o = ((size_t)(b0 + 3) * 4 + h) * 128;
      if (tid < 64) {
        float dq = bp[j] + bp[64 + j] + bp[128 + j] + bp[192 + j];
        float qs = th / fmaxf(sqrtf(fmaxf(dq + cqh, 0.f)), 1e-12f);
        norms[o + j] = (f16)qs;
      } else {
        float dk = bp[256 + j] + bp[320 + j] + bp[384 + j] + bp[448 + j];
        float ki = 1.f / fmaxf(sqrtf(fmaxf(dk, 0.f)), 1e-12f);
        norms[o + 64 + j] = (f16)ki;
      }
    }
  }
}

// ---------------- main fused kernel (unchanged from round 9) ----------------
__global__ __launch_bounds__(1024, 1) void k_msa(
    const float* __restrict__ E, const u16* __restrict__ BigB,
    const u16* __restrict__ NTg, const u16* __restrict__ biasTb,
    const float* __restrict__ augM, const float* __restrict__ w4,
    const f16* __restrict__ norms, const float* __restrict__ Ab,
    float* __restrict__ out) {
  extern __shared__ __align__(16) char lds[];
  u16* sEb   = (u16*)(lds);               // 2 x [64][136]  = 34816 B
  u16* sW    = (u16*)(lds + 34816);       // [128][136]     = 34816 B
  u16* sT1b  = (u16*)(lds + 69632);       // 2 x [64][136]  = 34816 B
  u16* sPb   = (u16*)(lds + 104448);      // 2 x [64][72]   = 18432 B
  u16* sENTb = (u16*)(lds + 122880);      // 2 x [128][72]  = 36864 B

  const int tid = threadIdx.x;
  const int wid = tid >> 6;
  const int w = wid >> 3;
  const int wv = wid & 7;
  const int lane = tid & 63;
  const int l15 = lane & 15;
  const int lk4 = (lane >> 4) << 2;
  const int lk8 = (lane >> 4) << 3;
  const int mt = wv >> 1;
  const int ch = wv & 1;
  const int j0 = ch * 32;
  const int onc = wv << 4;
  const size_t b = (size_t)blockIdx.x * 2 + w;

  u16* sE = sEb + w * 8704;
  u16* sT1 = sT1b + w * 8704;
  u16* sP = sPb + w * 4608;
  u16* sENT = sENTb + w * 9216;

  {
    const float4* E4 = (const float4*)(E + (size_t)blockIdx.x * 16384);
    #pragma unroll
    for (int it = 0; it < 4; ++it) {
      int i = tid + it * 1024;
      float4 v = E4[i];
      int ww = i >> 11, idx = i & 2047;
      int row = idx >> 5, c = (idx & 31) << 2;
      s16x4 u;
      u[0] = (short)f2bf(v.x); u[1] = (short)f2bf(v.y);
      u[2] = (short)f2bf(v.z); u[3] = (short)f2bf(v.w);
      *(s16x4*)&sEb[ww * 8704 + row * 136 + c] = u;
    }
    #pragma unroll
    for (int q = 0; q < 2; ++q) {
      int off = (q * 1024 + tid) * 8;
      int r = off >> 7, c = off & 127;
      *(s16x8*)&sW[r * 136 + c] = *(const s16x8*)&BigB[off];
    }
  }
  __syncthreads();

  const f32x4 zf4 = {0.f, 0.f, 0.f, 0.f};
  f32x4 oacc[4] = {zf4, zf4, zf4, zf4};
  s16x8 mr0, mr1, nr0, nr1;
  const int stg_r = tid >> 3;
  const int stg_c = (tid & 7) * 16;

  for (int h = 0; h < 4; ++h) {
    // ===== segment D(h-1)..A: commit M_h ; PV =====
    if (h > 0) {
      *(s16x8*)&sW[stg_r * 136 + stg_c] = mr0;
      *(s16x8*)&sW[stg_r * 136 + stg_c + 8] = mr1;
      #pragma unroll
      for (int ks = 0; ks < 2; ++ks) {
        const int koff = ks * 32 + lk8;
        bf16x8 a = *(const bf16x8*)&sP[(mt * 16 + l15) * 72 + koff];
        #pragma unroll
        for (int n = 0; n < 4; ++n) {
          bf16x8 bw = *(const bf16x8*)&sENT[(ch * 64 + n * 16 + l15) * 72 + koff];
          oacc[n] = MFMA(a, bw, oacc[n]);
        }
      }
    }
    __syncthreads();  // A: M_h committed & visible
    // ===== segment A..B: issue NT_h ; T1 = E M_h^T + augM =====
    {
      const u16* src = NTg + (size_t)h * 16384;
      nr0 = *(const s16x8*)&src[tid * 16];
      nr1 = *(const s16x8*)&src[tid * 16 + 8];
    }
    {
      f32x4 t1[4] = {zf4, zf4, zf4, zf4};
      #pragma unroll
      for (int ks = 0; ks < 4; ++ks) {
        const int koff = ks * 32 + lk8;
        bf16x8 bw = *(const bf16x8*)&sW[(onc + l15) * 136 + koff];
        #pragma unroll
        for (int m = 0; m < 4; ++m) {
          bf16x8 a = *(const bf16x8*)&sE[(m * 16 + l15) * 136 + koff];
          t1[m] = MFMA(a, bw, t1[m]);
        }
      }
      const float ta = augM[h * 128 + onc + l15];
      const int col = onc + l15;
      #pragma unroll
      for (int m = 0; m < 4; ++m)
        #pragma unroll
        for (int r = 0; r < 4; ++r)
          sT1[(m * 16 + lk4 + r) * 136 + col] = f2bf(t1[m][r] + ta);
    }
    __syncthreads();  // B: T1 done; sW reads (M_h) done
    // ===== segment B..C: commit NT_h ; S = T1 E^T =====
    *(s16x8*)&sW[stg_r * 136 + stg_c] = nr0;
    *(s16x8*)&sW[stg_r * 136 + stg_c + 8] = nr1;
    f32x4 s2[2] = {zf4, zf4};
    #pragma unroll
    for (int ks = 0; ks < 4; ++ks) {
      const int koff = ks * 32 + lk8;
      bf16x8 a = *(const bf16x8*)&sT1[(mt * 16 + l15) * 136 + koff];
      #pragma unroll
      for (int n = 0; n < 2; ++n) {
        bf16x8 bw = *(const bf16x8*)&sE[(j0 + n * 16 + l15) * 136 + koff];
        s2[n] = MFMA(a, bw, s2[n]);
      }
    }
    __syncthreads();  // C: NT_h committed & visible
    // ===== segment C..D: issue M_{h+1} ; EN = E NT_h + w4 ; epilogues =====
    if (h < 3) {
      const u16* src = BigB + (size_t)(h + 1) * 49152;
      mr0 = *(const s16x8*)&src[tid * 16];
      mr1 = *(const s16x8*)&src[tid * 16 + 8];
    }
    {
      f32x4 en[4] = {zf4, zf4, zf4, zf4};
      #pragma unroll
      for (int ks = 0; ks < 4; ++ks) {
        const int koff = ks * 32 + lk8;
        bf16x8 bw = *(const bf16x8*)&sW[(onc + l15) * 136 + koff];
        #pragma unroll
        for (int m = 0; m < 4; ++m) {
          bf16x8 a = *(const bf16x8*)&sE[(m * 16 + l15) * 136 + koff];
          en[m] = MFMA(a, bw, en[m]);
        }
      }
      const f16* nrm = norms + (((size_t)b * 4 + h) << 7);
      const int i0 = mt * 16 + lk4;
      float qs[4];
      #pragma unroll
      for (int r = 0; r < 4; ++r) qs[r] = (float)nrm[i0 + r];
      #pragma unroll
      for (int n = 0; n < 2; ++n) {
        const int j = j0 + n * 16 + l15;
        const float ki = (float)nrm[64 + j];
        s16x4 bb = *(const s16x4*)&biasTb[h * 4096 + j * 64 + i0];
        #pragma unroll
        for (int r = 0; r < 4; ++r)
          sP[(i0 + r) * 72 + j] = f2bf(fmaf(s2[n][r] * qs[r], ki, bf2f((u16)bb[r])));
      }
      const float wc = w4[h * 128 + onc + l15];
      #pragma unroll
      for (int m = 0; m < 4; ++m) {
        s16x4 u;
        u[0] = (short)f2bf(en[m][0] + wc); u[1] = (short)f2bf(en[m][1] + wc);
        u[2] = (short)f2bf(en[m][2] + wc); u[3] = (short)f2bf(en[m][3] + wc);
        *(s16x4*)&sENT[(onc + l15) * 72 + m * 16 + lk4] = u;
      }
    }
    __syncthreads();  // D: sP/sENT visible; sW reads (NT_h) done
  }

  // ---- tail: out += P_3 EN_3 ; + bias ; f32 store
  {
    #pragma unroll
    for (int ks = 0; ks < 2; ++ks) {
      const int koff = ks * 32 + lk8;
      bf16x8 a = *(const bf16x8*)&sP[(mt * 16 + l15) * 72 + koff];
      #pragma unroll
      for (int n = 0; n < 4; ++n) {
        bf16x8 bw = *(const bf16x8*)&sENT[(ch * 64 + n * 16 + l15) * 72 + koff];
        oacc[n] = MFMA(a, bw, oacc[n]);
      }
    }
    float* ob = out + b * 8192;
    #pragma unroll
    for (int n = 0; n < 4; ++n) {
      const int col = ch * 64 + n * 16 + l15;
      const float bv = Ab[col];
      #pragma unroll
      for (int r = 0; r < 4; ++r)
        ob[(mt * 16 + lk4 + r) * 128 + col] = oacc[n][r] + bv;
    }
  }
}

// ---------------- host ----------------
extern "C" void kernel_launch(void* const* d_in, const int* in_sizes, int n_in,
                              void* d_out, int out_size, void* d_ws, size_t ws_size,
                              hipStream_t stream) {
  const float* E    = (const float*)d_in[0];
  const float* rpos = (const float*)d_in[1];
  const int*   ridx = (const int*)d_in[2];
  const float* Wq   = (const float*)d_in[3];
  const float* Qb   = (const float*)d_in[4];
  const float* Wk   = (const float*)d_in[5];
  const float* Wv   = (const float*)d_in[6];
  const float* Vb   = (const float*)d_in[7];
  const float* Wa   = (const float*)d_in[8];
  const float* Ab   = (const float*)d_in[9];
  const float* w1   = (const float*)d_in[10];
  const float* b1   = (const float*)d_in[11];
  const float* w2   = (const float*)d_in[12];
  const float* ls   = (const float*)d_in[13];

  char* ws = (char*)d_ws;
  u16* BigB    = (u16*)(ws + 0);         // 4*3*128*128*2 = 393216
  u16* NTg     = (u16*)(ws + 393216);    // 4*128*128*2   = 131072
  u16* biasTb  = (u16*)(ws + 524288);    // 32768
  float* augM  = (float*)(ws + 557056);  // 2048
  float* augGq = (float*)(ws + 559104);  // 2048
  float* w4    = (float*)(ws + 561152);  // 2048
  float* cq4   = (float*)(ws + 563200);  // 64
  float* temp  = (float*)(ws + 563264);  // 64
  f16* norms   = (f16*)(ws + 563328);    // 1024*4*128*2 = 1048576

  hipFuncSetAttribute((const void*)k_prep,
                      hipFuncAttributeMaxDynamicSharedMemorySize, 102400);
  hipFuncSetAttribute((const void*)k_msa,
                      hipFuncAttributeMaxDynamicSharedMemorySize, 159744);
  hipFuncSetAttribute((const void*)k_norm,
                      hipFuncAttributeMaxDynamicSharedMemorySize, 143360);

  k_prep<<<17, 512, 102400, stream>>>(Wq, Wk, Wv, Wa, Qb, Vb, rpos, w1, b1, w2,
                                      ls, ridx, BigB, NTg, biasTb, augM, augGq,
                                      w4, cq4, temp);
  k_norm<<<256, 512, 143360, stream>>>(E, BigB, augGq, cq4, temp, norms);
  k_msa<<<512, 1024, 159744, stream>>>(E, BigB, NTg, biasTb, augM, w4,
                                       norms, Ab, (float*)d_out);
}

// Round 11
// 129.108 us; speedup vs baseline: 1.7976x; 1.0443x over previous
//
#include <hip/hip_runtime.h>
#include <hip/hip_bf16.h>
#include <cstdint>

typedef uint16_t u16;
typedef _Float16 f16;
typedef __attribute__((ext_vector_type(8))) __bf16 bf16x8;
typedef __attribute__((ext_vector_type(4))) short s16x4;
typedef __attribute__((ext_vector_type(8))) short s16x8;
typedef __attribute__((ext_vector_type(4))) float f32x4;

#define MFMA(a, b, c) __builtin_amdgcn_mfma_f32_16x16x32_bf16((a), (b), (c), 0, 0, 0)
#define LOG100 4.6051701859880914f

__device__ __forceinline__ u16 f2bf(float f) {
  union { float f; uint32_t u; } v; v.f = f;
  uint32_t u = v.u;
  return (u16)((u + 0x7FFFu + ((u >> 16) & 1u)) >> 16);
}
__device__ __forceinline__ float bf2f(u16 s) {
  union { uint32_t u; float f; } v; v.u = ((uint32_t)s) << 16;
  return v.f;
}

union U8 { s16x8 s; bf16x8 b; };

__device__ __forceinline__ bf16x8 ld_bf8(const float* __restrict__ p) {
  float4 v0 = *(const float4*)p;
  float4 v1 = *(const float4*)(p + 4);
  U8 u;
  u.s[0] = (short)f2bf(v0.x); u.s[1] = (short)f2bf(v0.y);
  u.s[2] = (short)f2bf(v0.z); u.s[3] = (short)f2bf(v0.w);
  u.s[4] = (short)f2bf(v1.x); u.s[5] = (short)f2bf(v1.y);
  u.s[6] = (short)f2bf(v1.z); u.s[7] = (short)f2bf(v1.w);
  return u.b;
}
__device__ __forceinline__ bf16x8 zero_bf8() {
  U8 u;
  #pragma unroll
  for (int e = 0; e < 8; ++e) u.s[e] = 0;
  return u.b;
}

// ---------------- prep kernel: 17 blocks x 512 thr ----------------
// blocks 0..15 = (h, t) Gram-type products (LDS-staged, reg-pipelined loads);
// block 16: bias table (lane-parallel MLP) + temp + cq4
__global__ __launch_bounds__(512) void k_prep(
    const float* __restrict__ Wq, const float* __restrict__ Wk,
    const float* __restrict__ Wv, const float* __restrict__ Wa,
    const float* __restrict__ Qb, const float* __restrict__ Vb,
    const float* __restrict__ rpos, const float* __restrict__ w1,
    const float* __restrict__ b1, const float* __restrict__ w2,
    const float* __restrict__ ls, const int* __restrict__ ridx,
    u16* __restrict__ BigB, u16* __restrict__ NTg, u16* __restrict__ biasTb,
    float* __restrict__ augM, float* __restrict__ augGq,
    float* __restrict__ w4, float* __restrict__ cq4, float* __restrict__ temp) {
  extern __shared__ __align__(16) char lds[];
  const int bid = blockIdx.x;
  const int tid = threadIdx.x;

  if (bid == 16) {
    float* tbl = (float*)lds;                  // [225][4]
    const int wv8 = tid >> 6;
    const int lane = tid & 63;
    // lane-parallel MLP: each row's 512-wide sum split 8 c's per lane
    for (int row = wv8; row < 225; row += 8) {
      const float x0 = rpos[row * 2 + 0], x1 = rpos[row * 2 + 1];
      float a0 = 0.f, a1 = 0.f, a2 = 0.f, a3 = 0.f;
      #pragma unroll
      for (int k = 0; k < 8; ++k) {
        const int c = k * 64 + lane;
        float hv = fmaxf(fmaf(x0, w1[c], fmaf(x1, w1[512 + c], b1[c])), 0.f);
        a0 = fmaf(hv, w2[c * 4 + 0], a0);
        a1 = fmaf(hv, w2[c * 4 + 1], a1);
        a2 = fmaf(hv, w2[c * 4 + 2], a2);
        a3 = fmaf(hv, w2[c * 4 + 3], a3);
      }
      #pragma unroll
      for (int off = 1; off < 64; off <<= 1) {
        a0 += __shfl_xor(a0, off); a1 += __shfl_xor(a1, off);
        a2 += __shfl_xor(a2, off); a3 += __shfl_xor(a3, off);
      }
      if (lane == 0) {
        tbl[row * 4 + 0] = a0; tbl[row * 4 + 1] = a1;
        tbl[row * 4 + 2] = a2; tbl[row * 4 + 3] = a3;
      }
    }
    if (tid < 4) temp[tid] = expf(fminf(ls[tid], LOG100));
    if (tid < 256) {
      int hh = tid >> 6, l = tid & 63;
      float s = 0.f;
      #pragma unroll
      for (int p = 0; p < 6; ++p) {
        float v = Qb[hh * 384 + l * 6 + p];
        s = fmaf(v, v, s);
      }
      s += __shfl_xor(s, 1); s += __shfl_xor(s, 2); s += __shfl_xor(s, 4);
      s += __shfl_xor(s, 8); s += __shfl_xor(s, 16); s += __shfl_xor(s, 32);
      if (l == 0) cq4[hh] = s;
    }
    __syncthreads();
    for (int it = 0; it < 32; ++it) {
      int gid = it * 512 + tid;
      int h = gid >> 12;
      int rem = gid & 4095;
      int q = rem >> 6, p = rem & 63;
      int ii = ((p >> 3) << 3) + (q >> 3);
      int jj = ((p & 7) << 3) + (q & 7);
      float v = tbl[ridx[ii * 64 + jj] * 4 + h];
      biasTb[gid] = f2bf(16.f / (1.f + expf(-v)));
    }
    return;
  }

  u16* sA = (u16*)lds;                 // [128][200] bf16 = 51200 B
  u16* sB = (u16*)(lds + 51200);       // [128][200] bf16 = 51200 B

  const int h = bid >> 2, t = bid & 3;
  const int wid = tid >> 6, lane = tid & 63;
  const int l15 = lane & 15, lk4 = (lane >> 4) << 2, lk8 = (lane >> 4) << 3;
  const f32x4 zf4 = {0.f, 0.f, 0.f, 0.f};

  const float* Asrc = (t == 2) ? Wk : ((t == 3) ? Wv : Wq);
  const u16* sBr = (t == 1 || t == 2) ? sA : sB;  // Gram blocks alias B=A
  const bool haveQ = (t == 1 || t == 2);
  const float sc = (t == 1) ? 2.f : 1.f;

  f32x4 acc[8], accq[8], accv;
  #pragma unroll
  for (int m = 0; m < 8; ++m) { acc[m] = zf4; accq[m] = zf4; }
  accv = zf4;

  for (int chunk = 0; chunk < 2; ++chunk) {
    const int gbase = h * 384 + chunk * 192;
    __syncthreads();   // previous chunk's LDS reads done
    // ---- issue all panel loads to regs first (pipelined), then LDS-write
    float4 va[12], vb[12];
    #pragma unroll
    for (int it = 0; it < 12; ++it) {
      int idx = it * 512 + tid;
      int row = idx / 48;
      int c4 = (idx - row * 48) * 4;
      va[it] = *(const float4*)&Asrc[(size_t)row * 1536 + gbase + c4];
    }
    if (t == 0) {
      #pragma unroll
      for (int it = 0; it < 12; ++it) {
        int idx = it * 512 + tid;
        int row = idx / 48;
        int c4 = (idx - row * 48) * 4;
        vb[it] = *(const float4*)&Wk[(size_t)row * 1536 + gbase + c4];
      }
    } else if (t == 3) {
      #pragma unroll
      for (int it = 0; it < 12; ++it) {
        int idx = it * 512 + tid;
        int a = idx >> 5;
        int c4 = (idx & 31) << 2;
        vb[it] = *(const float4*)&Wa[(size_t)(gbase + a) * 128 + c4];
      }
    }
    #pragma unroll
    for (int it = 0; it < 12; ++it) {
      int idx = it * 512 + tid;
      int row = idx / 48;
      int c4 = (idx - row * 48) * 4;
      s16x4 u;
      u[0] = (short)f2bf(va[it].x); u[1] = (short)f2bf(va[it].y);
      u[2] = (short)f2bf(va[it].z); u[3] = (short)f2bf(va[it].w);
      *(s16x4*)&sA[row * 200 + c4] = u;
    }
    if (t == 0) {
      #pragma unroll
      for (int it = 0; it < 12; ++it) {
        int idx = it * 512 + tid;
        int row = idx / 48;
        int c4 = (idx - row * 48) * 4;
        s16x4 u;
        u[0] = (short)f2bf(vb[it].x); u[1] = (short)f2bf(vb[it].y);
        u[2] = (short)f2bf(vb[it].z); u[3] = (short)f2bf(vb[it].w);
        *(s16x4*)&sB[row * 200 + c4] = u;
      }
    } else if (t == 3) {
      #pragma unroll
      for (int it = 0; it < 12; ++it) {
        int idx = it * 512 + tid;
        int a = idx >> 5;
        int c4 = (idx & 31) << 2;
        sB[(c4 + 0) * 200 + a] = f2bf(vb[it].x);
        sB[(c4 + 1) * 200 + a] = f2bf(vb[it].y);
        sB[(c4 + 2) * 200 + a] = f2bf(vb[it].z);
        sB[(c4 + 3) * 200 + a] = f2bf(vb[it].w);
      }
    }
    // ---- preload aug vectors for this chunk (hoisted out of MFMA loop)
    bf16x8 bq[6], av6[6];
    if (haveQ && wid == 0) {
      #pragma unroll
      for (int ks = 0; ks < 6; ++ks)
        bq[ks] = (l15 == 0) ? ld_bf8(&Qb[gbase + ks * 32 + lk8]) : zero_bf8();
    }
    if (t == 3) {
      #pragma unroll
      for (int ks = 0; ks < 6; ++ks)
        av6[ks] = (l15 == 0) ? ld_bf8(&Vb[gbase + ks * 32 + lk8]) : zero_bf8();
    }
    __syncthreads();
    // ---- MFMA from LDS: wave wid owns B-tile wid; all 8 A-tiles
    #pragma unroll
    for (int ks = 0; ks < 6; ++ks) {
      const int koff = ks * 32 + lk8;
      bf16x8 bw = *(const bf16x8*)&sBr[(wid * 16 + l15) * 200 + koff];
      bf16x8 a[8];
      #pragma unroll
      for (int m = 0; m < 8; ++m)
        a[m] = *(const bf16x8*)&sA[(m * 16 + l15) * 200 + koff];
      #pragma unroll
      for (int m = 0; m < 8; ++m)
        acc[m] = MFMA(a[m], bw, acc[m]);
      if (haveQ && wid == 0) {
        #pragma unroll
        for (int m = 0; m < 8; ++m)
          accq[m] = MFMA(a[m], bq[ks], accq[m]);
      }
      if (t == 3)
        accv = MFMA(av6[ks], bw, accv);
    }
  }

  // ---- stores
  u16* dst = (t < 3) ? (BigB + (size_t)(h * 3 + t) * 16384)
                     : (NTg + (size_t)h * 16384);
  #pragma unroll
  for (int m = 0; m < 8; ++m) {
    s16x4 u;
    u[0] = (short)f2bf(acc[m][0]); u[1] = (short)f2bf(acc[m][1]);
    u[2] = (short)f2bf(acc[m][2]); u[3] = (short)f2bf(acc[m][3]);
    *(s16x4*)&dst[(wid * 16 + l15) * 128 + m * 16 + lk4] = u;
  }
  if (haveQ && wid == 0 && l15 == 0) {
    float* tgt = (t == 1) ? augGq : augM;
    #pragma unroll
    for (int m = 0; m < 8; ++m)
      #pragma unroll
      for (int r = 0; r < 4; ++r)
        tgt[h * 128 + m * 16 + lk4 + r] = sc * accq[m][r];
  }
  if (t == 3 && lane < 16)
    w4[h * 128 + wid * 16 + lane] = accv[0];
}

// ---------------- norm kernel (unchanged) ----------------
__global__ __launch_bounds__(512, 1) void k_norm(
    const float* __restrict__ E, const u16* __restrict__ BigB,
    const float* __restrict__ augGq, const float* __restrict__ cq4,
    const float* __restrict__ temp, f16* __restrict__ norms) {
  extern __shared__ __align__(16) char lds[];
  u16* sE4 = (u16*)lds;                 // 4 x [64][136] = 69632 B
  u16* sG = (u16*)(lds + 69632);        // [256][136]    = 69632 B
  float* sDp = (float*)(lds + 139264);  // [2][8][64]    = 4096 B

  const int tid = threadIdx.x;
  const int wv = tid >> 6, lane = tid & 63;
  const int l15 = lane & 15, lk4 = (lane >> 4) << 2, lk8 = (lane >> 4) << 3;
  const int rw = (wv & 3) * 32;
  const int b0 = blockIdx.x * 4;
  const f32x4 zf4 = {0.f, 0.f, 0.f, 0.f};

  {
    const float4* E4 = (const float4*)(E + (size_t)b0 * 8192);
    #pragma unroll
    for (int it = 0; it < 16; ++it) {
      int i = tid + it * 512;
      float4 v = E4[i];
      int ww = i >> 11, idx = i & 2047;
      int row = idx >> 5, c = (idx & 31) << 2;
      s16x4 u;
      u[0] = (short)f2bf(v.x); u[1] = (short)f2bf(v.y);
      u[2] = (short)f2bf(v.z); u[3] = (short)f2bf(v.w);
      *(s16x4*)&sE4[ww * 8704 + row * 136 + c] = u;
    }
  }

  for (int h = 0; h < 4; ++h) {
    __syncthreads();
    {
      const u16* src = BigB + (size_t)(h * 3 + 1) * 16384;
      #pragma unroll
      for (int q = 0; q < 8; ++q) {
        int off = (q * 512 + tid) * 8;
        int r = off >> 7, c = off & 127;
        *(s16x8*)&sG[r * 136 + c] = *(const s16x8*)&src[off];
      }
    }
    const float th = temp[h], cqh = cq4[h];
    float aq[2][4];
    #pragma unroll
    for (int mm = 0; mm < 2; ++mm)
      #pragma unroll
      for (int r = 0; r < 4; ++r)
        aq[mm][r] = (wv < 4) ? augGq[h * 128 + rw + mm * 16 + lk4 + r] : 0.f;
    __syncthreads();

    for (int wi = 0; wi < 4; ++wi) {
      const u16* sE = &sE4[wi * 8704];
      const u16* Gw = &sG[(((wv < 4) ? 0 : 128) + rw) * 136];
      f32x4 z[2][4];
      #pragma unroll
      for (int mm = 0; mm < 2; ++mm)
        #pragma unroll
        for (int n = 0; n < 4; ++n) z[mm][n] = zf4;
      #pragma unroll
      for (int ks = 0; ks < 4; ++ks) {
        const int koff = ks * 32 + lk8;
        bf16x8 a0 = *(const bf16x8*)&Gw[l15 * 136 + koff];
        bf16x8 a1 = *(const bf16x8*)&Gw[(16 + l15) * 136 + koff];
        #pragma unroll
        for (int n = 0; n < 4; ++n) {
          bf16x8 bw = *(const bf16x8*)&sE[(n * 16 + l15) * 136 + koff];
          z[0][n] = MFMA(a0, bw, z[0][n]);
          z[1][n] = MFMA(a1, bw, z[1][n]);
        }
      }
      #pragma unroll
      for (int n = 0; n < 4; ++n) {
        const int j = n * 16 + l15;
        float p = 0.f;
        #pragma unroll
        for (int mm = 0; mm < 2; ++mm)
          #pragma unroll
          for (int r = 0; r < 4; ++r)
            p = fmaf(z[mm][n][r] + aq[mm][r],
                     bf2f(sE[j * 136 + rw + mm * 16 + lk4 + r]), p);
        p += __shfl_xor(p, 16);
        p += __shfl_xor(p, 32);
        if (lane < 16) sDp[((wi & 1) * 8 + wv) * 64 + j] = p;
      }
      if (wi > 0 && tid < 128) {
        const int pw = wi - 1;
        const float* bp = &sDp[((pw & 1) * 8) * 64];
        const int j = tid & 63;
        const size_t o = ((size_t)(b0 + pw) * 4 + h) * 128;
        if (tid < 64) {
          float dq = bp[j] + bp[64 + j] + bp[128 + j] + bp[192 + j];
          float qs = th / fmaxf(sqrtf(fmaxf(dq + cqh, 0.f)), 1e-12f);
          norms[o + j] = (f16)qs;
        } else {
          float dk = bp[256 + j] + bp[320 + j] + bp[384 + j] + bp[448 + j];
          float ki = 1.f / fmaxf(sqrtf(fmaxf(dk, 0.f)), 1e-12f);
          norms[o + 64 + j] = (f16)ki;
        }
      }
      __syncthreads();
    }
    if (tid < 128) {
      const float* bp = &sDp[8 * 64];
      const int j = tid & 63;
      const size_t o = ((size_t)(b0 + 3) * 4 + h) * 128;
      if (tid < 64) {
        float dq = bp[j] + bp[64 + j] + bp[128 + j] + bp[192 + j];
        float qs = th / fmaxf(sqrtf(fmaxf(dq + cqh, 0.f)), 1e-12f);
        norms[o + j] = (f16)qs;
      } else {
        float dk = bp[256 + j] + bp[320 + j] + bp[384 + j] + bp[448 + j];
        float ki = 1.f / fmaxf(sqrtf(fmaxf(dk, 0.f)), 1e-12f);
        norms[o + 64 + j] = (f16)ki;
      }
    }
  }
}

// ---------------- main fused kernel ----------------
// 1 block = 1 window, 512 thr = 8 waves, 79872 B LDS -> 2 blocks/CU
// (independent 8-wave barrier groups overlap). T1 and ENT share one buffer
// (liveness-disjoint: T1 live A->B, ENT live C->next-A).
__global__ __launch_bounds__(512, 4) void k_msa(
    const float* __restrict__ E, const u16* __restrict__ BigB,
    const u16* __restrict__ NTg, const u16* __restrict__ biasTb,
    const float* __restrict__ augM, const float* __restrict__ w4,
    const f16* __restrict__ norms, const float* __restrict__ Ab,
    float* __restrict__ out) {
  extern __shared__ __align__(16) char lds[];
  u16* sE  = (u16*)(lds);               // [64][136]  = 17408 B
  u16* sW  = (u16*)(lds + 17408);       // [128][136] = 34816 B (M_h / NT_h time-shared)
  u16* sTE = (u16*)(lds + 52224);       // max(T1 [64][136]=17408, ENT [128][72]=18432)
  u16* sP  = (u16*)(lds + 70656);       // [64][72]   = 9216 B
  // total 79872 B

  const int tid = threadIdx.x;
  const int wv = tid >> 6;
  const int lane = tid & 63;
  const int l15 = lane & 15;
  const int lk4 = (lane >> 4) << 2;
  const int lk8 = (lane >> 4) << 3;
  const int mt = wv >> 1;
  const int ch = wv & 1;
  const int j0 = ch * 32;
  const int onc = wv << 4;
  const size_t b = blockIdx.x;

  // ---- prologue: stage E + M_0 (direct to sW)
  {
    const float4* E4 = (const float4*)(E + b * 8192);
    #pragma unroll
    for (int it = 0; it < 4; ++it) {
      int i = tid + it * 512;                 // 2048 float4
      float4 v = E4[i];
      int row = i >> 5, c = (i & 31) << 2;
      s16x4 u;
      u[0] = (short)f2bf(v.x); u[1] = (short)f2bf(v.y);
      u[2] = (short)f2bf(v.z); u[3] = (short)f2bf(v.w);
      *(s16x4*)&sE[row * 136 + c] = u;
    }
    const int r = tid >> 2, c0 = (tid & 3) * 32;
    #pragma unroll
    for (int k = 0; k < 4; ++k)
      *(s16x8*)&sW[r * 136 + c0 + k * 8] = *(const s16x8*)&BigB[tid * 32 + k * 8];
  }
  __syncthreads();

  const f32x4 zf4 = {0.f, 0.f, 0.f, 0.f};
  f32x4 oacc[4] = {zf4, zf4, zf4, zf4};
  s16x8 mr[4], nr[4];
  const int stg_r = tid >> 2;
  const int stg_c = (tid & 3) * 32;

  for (int h = 0; h < 4; ++h) {
    // ===== segment D(h-1)..A: commit M_h ; PV =====
    if (h > 0) {
      #pragma unroll
      for (int k = 0; k < 4; ++k)
        *(s16x8*)&sW[stg_r * 136 + stg_c + k * 8] = mr[k];
      // PV: out += P_{h-1} @ EN_{h-1}   (ENT in sTE)
      #pragma unroll
      for (int ks = 0; ks < 2; ++ks) {
        const int koff = ks * 32 + lk8;
        bf16x8 a = *(const bf16x8*)&sP[(mt * 16 + l15) * 72 + koff];
        #pragma unroll
        for (int n = 0; n < 4; ++n) {
          bf16x8 bw = *(const bf16x8*)&sTE[(ch * 64 + n * 16 + l15) * 72 + koff];
          oacc[n] = MFMA(a, bw, oacc[n]);
        }
      }
    }
    __syncthreads();  // A: M_h committed & visible; ENT reads done
    // ===== segment A..B: issue NT_h ; T1 = E M_h^T + augM -> sTE =====
    {
      const u16* src = NTg + (size_t)h * 16384;
      #pragma unroll
      for (int k = 0; k < 4; ++k)
        nr[k] = *(const s16x8*)&src[tid * 32 + k * 8];
    }
    {
      f32x4 t1[4] = {zf4, zf4, zf4, zf4};
      #pragma unroll
      for (int ks = 0; ks < 4; ++ks) {
        const int koff = ks * 32 + lk8;
        bf16x8 bw = *(const bf16x8*)&sW[(onc + l15) * 136 + koff];
        #pragma unroll
        for (int m = 0; m < 4; ++m) {
          bf16x8 a = *(const bf16x8*)&sE[(m * 16 + l15) * 136 + koff];
          t1[m] = MFMA(a, bw, t1[m]);
        }
      }
      const float ta = augM[h * 128 + onc + l15];
      const int col = onc + l15;
      #pragma unroll
      for (int m = 0; m < 4; ++m)
        #pragma unroll
        for (int r = 0; r < 4; ++r)
          sTE[(m * 16 + lk4 + r) * 136 + col] = f2bf(t1[m][r] + ta);
    }
    __syncthreads();  // B: T1 done; sW reads (M_h) done
    // ===== segment B..C: commit NT_h ; S = T1 E^T =====
    #pragma unroll
    for (int k = 0; k < 4; ++k)
      *(s16x8*)&sW[stg_r * 136 + stg_c + k * 8] = nr[k];
    f32x4 s2[2] = {zf4, zf4};
    #pragma unroll
    for (int ks = 0; ks < 4; ++ks) {
      const int koff = ks * 32 + lk8;
      bf16x8 a = *(const bf16x8*)&sTE[(mt * 16 + l15) * 136 + koff];
      #pragma unroll
      for (int n = 0; n < 2; ++n) {
        bf16x8 bw = *(const bf16x8*)&sE[(j0 + n * 16 + l15) * 136 + koff];
        s2[n] = MFMA(a, bw, s2[n]);
      }
    }
    __syncthreads();  // C: NT_h committed & visible; T1 reads done
    // ===== segment C..D: issue M_{h+1} ; EN = E NT_h ; epilogues =====
    if (h < 3) {
      const u16* src = BigB + (size_t)(h + 1) * 49152;
      #pragma unroll
      for (int k = 0; k < 4; ++k)
        mr[k] = *(const s16x8*)&src[tid * 32 + k * 8];
    }
    {
      f32x4 en[4] = {zf4, zf4, zf4, zf4};
      #pragma unroll
      for (int ks = 0; ks < 4; ++ks) {
        const int koff = ks * 32 + lk8;
        bf16x8 bw = *(const bf16x8*)&sW[(onc + l15) * 136 + koff];
        #pragma unroll
        for (int m = 0; m < 4; ++m) {
          bf16x8 a = *(const bf16x8*)&sE[(m * 16 + l15) * 136 + koff];
          en[m] = MFMA(a, bw, en[m]);
        }
      }
      // P epilogue (norms precomputed; qs includes temp)
      const f16* nrm = norms + ((b * 4 + h) << 7);
      const int i0 = mt * 16 + lk4;
      float qs[4];
      #pragma unroll
      for (int r = 0; r < 4; ++r) qs[r] = (float)nrm[i0 + r];
      #pragma unroll
      for (int n = 0; n < 2; ++n) {
        const int j = j0 + n * 16 + l15;
        const float ki = (float)nrm[64 + j];
        s16x4 bb = *(const s16x4*)&biasTb[h * 4096 + j * 64 + i0];
        #pragma unroll
        for (int r = 0; r < 4; ++r)
          sP[(i0 + r) * 72 + j] = f2bf(fmaf(s2[n][r] * qs[r], ki, bf2f((u16)bb[r])));
      }
      // EN epilogue: transposed store into sTE (as ENT)
      const float wc = w4[h * 128 + onc + l15];
      #pragma unroll
      for (int m = 0; m < 4; ++m) {
        s16x4 u;
        u[0] = (short)f2bf(en[m][0] + wc); u[1] = (short)f2bf(en[m][1] + wc);
        u[2] = (short)f2bf(en[m][2] + wc); u[3] = (short)f2bf(en[m][3] + wc);
        *(s16x4*)&sTE[(onc + l15) * 72 + m * 16 + lk4] = u;
      }
    }
    __syncthreads();  // D: sP/sENT visible; sW reads (NT_h) done
  }

  // ---- tail: out += P_3 EN_3 ; + bias ; f32 store
  {
    #pragma unroll
    for (int ks = 0; ks < 2; ++ks) {
      const int koff = ks * 32 + lk8;
      bf16x8 a = *(const bf16x8*)&sP[(mt * 16 + l15) * 72 + koff];
      #pragma unroll
      for (int n = 0; n < 4; ++n) {
        bf16x8 bw = *(const bf16x8*)&sTE[(ch * 64 + n * 16 + l15) * 72 + koff];
        oacc[n] = MFMA(a, bw, oacc[n]);
      }
    }
    float* ob = out + b * 8192;
    #pragma unroll
    for (int n = 0; n < 4; ++n) {
      const int col = ch * 64 + n * 16 + l15;
      const float bv = Ab[col];
      #pragma unroll
      for (int r = 0; r < 4; ++r)
        ob[(mt * 16 + lk4 + r) * 128 + col] = oacc[n][r] + bv;
    }
  }
}

// ---------------- host ----------------
extern "C" void kernel_launch(void* const* d_in, const int* in_sizes, int n_in,
                              void* d_out, int out_size, void* d_ws, size_t ws_size,
                              hipStream_t stream) {
  const float* E    = (const float*)d_in[0];
  const float* rpos = (const float*)d_in[1];
  const int*   ridx = (const int*)d_in[2];
  const float* Wq   = (const float*)d_in[3];
  const float* Qb   = (const float*)d_in[4];
  const float* Wk   = (const float*)d_in[5];
  const float* Wv   = (const float*)d_in[6];
  const float* Vb   = (const float*)d_in[7];
  const float* Wa   = (const float*)d_in[8];
  const float* Ab   = (const float*)d_in[9];
  const float* w1   = (const float*)d_in[10];
  const float* b1   = (const float*)d_in[11];
  const float* w2   = (const float*)d_in[12];
  const float* ls   = (const float*)d_in[13];

  char* ws = (char*)d_ws;
  u16* BigB    = (u16*)(ws + 0);         // 4*3*128*128*2 = 393216
  u16* NTg     = (u16*)(ws + 393216);    // 4*128*128*2   = 131072
  u16* biasTb  = (u16*)(ws + 524288);    // 32768
  float* augM  = (float*)(ws + 557056);  // 2048
  float* augGq = (float*)(ws + 559104);  // 2048
  float* w4    = (float*)(ws + 561152);  // 2048
  float* cq4   = (float*)(ws + 563200);  // 64
  float* temp  = (float*)(ws + 563264);  // 64
  f16* norms   = (f16*)(ws + 563328);    // 1024*4*128*2 = 1048576

  hipFuncSetAttribute((const void*)k_prep,
                      hipFuncAttributeMaxDynamicSharedMemorySize, 102400);
  hipFuncSetAttribute((const void*)k_msa,
                      hipFuncAttributeMaxDynamicSharedMemorySize, 79872);
  hipFuncSetAttribute((const void*)k_norm,
                      hipFuncAttributeMaxDynamicSharedMemorySize, 143360);

  k_prep<<<17, 512, 102400, stream>>>(Wq, Wk, Wv, Wa, Qb, Vb, rpos, w1, b1, w2,
                                      ls, ridx, BigB, NTg, biasTb, augM, augGq,
                                      w4, cq4, temp);
  k_norm<<<256, 512, 143360, stream>>>(E, BigB, augGq, cq4, temp, norms);
  k_msa<<<1024, 512, 79872, stream>>>(E, BigB, NTg, biasTb, augM, w4,
                                      norms, Ab, (float*)d_out);
}